// Round 1
// 294.049 us; speedup vs baseline: 1.0504x; 1.0504x over previous
//
#include <hip/hip_runtime.h>

// ---------------------------------------------------------------------------
// LinearAttention (b=8, c=512, l=4096, heads=8, dim_head=64)
//   xn = rmsnorm_ch(x, g_in); qkv = W_qkv @ xn
//   q = softmax_d(q)*scale; k = softmax_l(k)
//   ctx = k v^T; out = ctx^T q; o = rmsnorm_ch(W_out @ out + b_out) + x
// GEMMs: 256x256 8-phase pipelined schedule (T2 swizzle + T3/T4 counted
// vmcnt + T5 setprio), 8 waves, 128 KB LDS double-buffer, 16x16x32 MFMA.
// Counted vmcnt(6) once per K-tile -- loads stay in flight across barriers.
// ---------------------------------------------------------------------------

#define BB 8
#define CC 512
#define LL 4096
#define HH 8
#define DH 64
#define TC 1536

__device__ __constant__ const float SQRT_C = 22.62741699796952f;   // sqrt(512)
#define SCALE_Q 0.125f                                             // 64^-0.5

typedef unsigned short bfr_t;
typedef __attribute__((ext_vector_type(8))) short short8;
typedef __attribute__((ext_vector_type(4))) float f32x4;
typedef __attribute__((ext_vector_type(16))) float f32x16;

__device__ __forceinline__ float bf2f(bfr_t v) {
  union { unsigned u; float f; } c; c.u = ((unsigned)v) << 16; return c.f;
}
__device__ __forceinline__ bfr_t f2bf(float f) {
  union { float f; unsigned u; } c; c.f = f;
  unsigned u = c.u + 0x7fffu + ((c.u >> 16) & 1u);   // RNE, ignores NaN edge
  return (bfr_t)(u >> 16);
}

__device__ __forceinline__ void load_lds16(const bfr_t* g, short* l) {
  __builtin_amdgcn_global_load_lds(
      (const __attribute__((address_space(1))) void*)g,
      (__attribute__((address_space(3))) void*)l, 16, 0, 0);
}

// -------- f32 -> bf16 convert (both weights, vectorized x8, 1 launch) ------
__global__ __launch_bounds__(256) void conv_bf16_2(
    const float* __restrict__ in1, bfr_t* __restrict__ o1, int n1,
    const float* __restrict__ in2, bfr_t* __restrict__ o2, int n2) {
  int i8 = (blockIdx.x * 256 + threadIdx.x) * 8;
  const float* src;
  bfr_t* dst;
  if (i8 < n1) { src = in1 + i8; dst = o1 + i8; }
  else {
    int j8 = i8 - n1;
    if (j8 >= n2) return;
    src = in2 + j8; dst = o2 + j8;
  }
  f32x4 a = *(const f32x4*)src;
  f32x4 b = *(const f32x4*)(src + 4);
  union { short s[8]; f32x4 v; } pk;
#pragma unroll
  for (int u = 0; u < 4; ++u) { pk.s[u] = (short)f2bf(a[u]); pk.s[u + 4] = (short)f2bf(b[u]); }
  *(f32x4*)dst = pk.v;
}

// ------ fused channel-RMSNorm + transpose: x[b][c][l] -> xt[b][l][c] -------
__global__ __launch_bounds__(256) void fused_norm_transpose(
    const float* __restrict__ x, const float* __restrict__ g,
    bfr_t* __restrict__ xt) {
  __shared__ float tile[64][65];
  __shared__ float red[4][64];
  __shared__ float invn_s[64];
  int b = blockIdx.y, l0 = blockIdx.x * 64;
  int t = threadIdx.x, ll = t & 63, cg = t >> 6;
  const float* xb = x + (size_t)b * CC * LL + l0;
  float vals[8][16];
  float ss = 0.f;
#pragma unroll
  for (int ch = 0; ch < 8; ++ch) {
    int c0 = ch * 64;
#pragma unroll
    for (int i = 0; i < 16; ++i) {
      int c = i * 4 + cg;                       // chunk-local channel
      float v = xb[(size_t)(c0 + c) * LL + ll];
      vals[ch][i] = v;
      ss += v * v;
    }
  }
  red[cg][ll] = ss;
  __syncthreads();
  if (cg == 0) {
    float s = red[0][ll] + red[1][ll] + red[2][ll] + red[3][ll];
    invn_s[ll] = SQRT_C / fmaxf(sqrtf(s), 1e-12f);
  }
  __syncthreads();
  int lw = t >> 2, ccw = (t & 3) * 16;
  float iv = invn_s[lw];
#pragma unroll
  for (int ch = 0; ch < 8; ++ch) {
    int c0 = ch * 64;
#pragma unroll
    for (int i = 0; i < 16; ++i) tile[i * 4 + cg][ll] = vals[ch][i];
    __syncthreads();
    union { short s[16]; f32x4 v[2]; } pk;
#pragma unroll
    for (int u = 0; u < 16; ++u) {
      int c = ccw + u;
      pk.s[u] = (short)f2bf(tile[c][lw] * g[c0 + c] * iv);
    }
    bfr_t* dst = xt + ((size_t)b * LL + l0 + lw) * CC + c0 + ccw;
    *(f32x4*)dst = pk.v[0];
    *(f32x4*)(dst + 8) = pk.v[1];
    __syncthreads();
  }
}

// ----------------------- 256x256 8-phase bf16 GEMM -------------------------
// C[b][m][n] = sum_k A[m][k] * Bt[b][n][k] (+ bias[m]); A:[M][512], Bt:[B][L][512]
// 8 waves (2M x 4N), per-wave 128x64 out. LDS: 2 dbuf x 2 half x [128][64]
// per operand = 128 KB. Per K-tile: 4 phases, each {ds_read, stage half-tile,
// barrier, lgkmcnt(0), setprio(1), 16 MFMA, setprio(0), barrier}; one counted
// vmcnt(6) per K-tile (never 0 mid-loop). 16B-granule XOR swizzle both sides.
// grid (L/256, M/256, B), block 512.
#define NT 8                                      // K-tiles (K=512, BK=64)

__device__ __forceinline__ void stage_half(const bfr_t* g, short* l, int wid) {
  // g is lane-adjusted (soff folded in); 2 chunks of 8 rows per wave
  load_lds16(g + (size_t)wid * 8192,        l + wid * 1024);
  load_lds16(g + (size_t)wid * 8192 + 4096, l + wid * 1024 + 512);
}

#define CFENCE asm volatile("" ::: "memory")
#define PHASE_MID()                                          \
  do { CFENCE; __builtin_amdgcn_s_barrier();                 \
       asm volatile("s_waitcnt lgkmcnt(0)" ::: "memory");    \
       __builtin_amdgcn_sched_barrier(0); } while (0)
#define PHASE_END()                                          \
  do { CFENCE; __builtin_amdgcn_s_barrier(); CFENCE; } while (0)

#define LOAD_A(QM) do {                                           \
    const short* ab_ = Ah + (QM) * 4096;                          \
    _Pragma("unroll") for (int i_ = 0; i_ < 4; ++i_) {            \
      a_reg[i_ * 2 + 0] = *(const short8*)(ab_ + i_ * 1024 + a_off0); \
      a_reg[i_ * 2 + 1] = *(const short8*)(ab_ + i_ * 1024 + a_off1); \
    } } while (0)

#define LOAD_B(QN) do {                                           \
    const short* bb_ = Bh + (QN) * 2048;                          \
    _Pragma("unroll") for (int j_ = 0; j_ < 2; ++j_) {            \
      b_reg[QN][j_ * 2 + 0] = *(const short8*)(bb_ + j_ * 1024 + b_off0); \
      b_reg[QN][j_ * 2 + 1] = *(const short8*)(bb_ + j_ * 1024 + b_off1); \
    } } while (0)

#define MMA_Q(QM, QN) do {                                                   \
    __builtin_amdgcn_s_setprio(1);                                           \
    _Pragma("unroll") for (int i_ = 0; i_ < 4; ++i_) {                       \
      _Pragma("unroll") for (int j_ = 0; j_ < 2; ++j_) {                     \
        acc[(QM) * 4 + i_][(QN) * 2 + j_] =                                  \
            __builtin_amdgcn_mfma_f32_16x16x32_bf16(                         \
                a_reg[i_ * 2 + 0], b_reg[QN][j_ * 2 + 0],                    \
                acc[(QM) * 4 + i_][(QN) * 2 + j_], 0, 0, 0);                 \
        acc[(QM) * 4 + i_][(QN) * 2 + j_] =                                  \
            __builtin_amdgcn_mfma_f32_16x16x32_bf16(                         \
                a_reg[i_ * 2 + 1], b_reg[QN][j_ * 2 + 1],                    \
                acc[(QM) * 4 + i_][(QN) * 2 + j_], 0, 0, 0);                 \
      } }                                                                    \
    __builtin_amdgcn_s_setprio(0); } while (0)

__global__ __launch_bounds__(512, 2) void gemm256(
    const bfr_t* __restrict__ A, const bfr_t* __restrict__ Bt,
    bfr_t* __restrict__ Cout, const float* __restrict__ bias, int M) {
  __shared__ short lds[65536];          // 128 KB
  short* As = lds;                      // [2 buf][2 half][128][64]
  short* Bs = lds + 32768;
  int bz = blockIdx.z;
  int m0 = blockIdx.y * 256, n0 = blockIdx.x * 256;
  int t = threadIdx.x, lane = t & 63, wid = t >> 6;
  int quad = lane >> 4, r16 = lane & 15;
  int wm = wid >> 2, wn = wid & 3;
  // staging source offset: row (lane>>3), pre-swizzled granule (l&7)^(l>>3)
  int soff = (lane >> 3) * 512 + (((lane & 7) ^ (lane >> 3)) * 8);
  // ds_read swizzled k-granule slots (row&7 == lane&7 for all fragments)
  int slot0 = (quad ^ (lane & 7)) * 8;          // ks=0
  int slot1 = ((4 + quad) ^ (lane & 7)) * 8;    // ks=1
  int a_off0 = r16 * 64 + slot0, a_off1 = r16 * 64 + slot1;
  int bb0 = ((wn & 1) * 64 + r16) * 64;
  int b_off0 = bb0 + slot0, b_off1 = bb0 + slot1;

  const bfr_t* pA0 = A + (size_t)m0 * 512 + soff;
  const bfr_t* pA1 = pA0 + (size_t)128 * 512;
  const bfr_t* pB0 = Bt + (size_t)bz * LL * 512 + (size_t)n0 * 512 + soff;
  const bfr_t* pB1 = pB0 + (size_t)128 * 512;

  f32x4 acc[8][4] = {};
  short8 a_reg[8];
  short8 b_reg[2][4];

  // ---- prologue: stage K-tiles 0 and 1 (16 loads/wave) ----
  stage_half(pA0, As, wid);                    // t0 A0 -> buf0
  stage_half(pA1, As + 8192, wid);             // t0 A1
  stage_half(pB0, Bs, wid);                    // t0 B0
  stage_half(pB1, Bs + 8192, wid);             // t0 B1
  stage_half(pA0 + 64, As + 16384, wid);       // t1 A0 -> buf1
  stage_half(pA1 + 64, As + 24576, wid);       // t1 A1
  stage_half(pB0 + 64, Bs + 16384, wid);       // t1 B0
  stage_half(pB1 + 64, Bs + 24576, wid);       // t1 B1
  asm volatile("s_waitcnt vmcnt(8)" ::: "memory");   // tile 0 landed
  CFENCE; __builtin_amdgcn_s_barrier(); CFENCE;

#pragma unroll
  for (int kt = 0; kt < NT; ++kt) {
    const int buf = kt & 1;
    const short* Ah = As + (buf * 2 + wm) * 8192;
    const short* Bh = Bs + (buf * 2 + (wn >> 1)) * 8192;
    // ---- phase 1: quadrant (qm=0, qn=0); stage A1(kt+1) -> buf^1 ----
    LOAD_A(0);
    LOAD_B(0);
    if (kt >= 1 && kt <= NT - 2)
      stage_half(pA1 + (kt + 1) * 64, As + (((kt + 1) & 1) * 2 + 1) * 8192, wid);
    PHASE_MID();
    MMA_Q(0, 0);
    PHASE_END();
    // ---- phase 2: (0,1) ----
    LOAD_B(1);
    PHASE_MID();
    MMA_Q(0, 1);
    PHASE_END();
    // ---- phase 3: (1,1); B halves of buf fully read -> stage B0(kt+2) ----
    LOAD_A(1);
    if (kt <= NT - 3)
      stage_half(pB0 + (kt + 2) * 64, Bs + (buf * 2) * 8192, wid);
    PHASE_MID();
    MMA_Q(1, 1);
    PHASE_END();
    // ---- phase 4: (1,0); A halves fully read -> stage B1,A0(kt+2) ----
    if (kt <= NT - 3) {
      stage_half(pB1 + (kt + 2) * 64, Bs + (buf * 2 + 1) * 8192, wid);
      stage_half(pA0 + (kt + 2) * 64, As + (buf * 2) * 8192, wid);
    }
    PHASE_MID();
    MMA_Q(1, 0);
    __builtin_amdgcn_sched_barrier(0);
    // counted vmcnt: next tile's data landed, 3 half-tiles stay in flight
    if (kt <= NT - 3)      { asm volatile("s_waitcnt vmcnt(6)" ::: "memory"); }
    else if (kt == NT - 2) { asm volatile("s_waitcnt vmcnt(0)" ::: "memory"); }
    CFENCE; __builtin_amdgcn_s_barrier(); CFENCE;
  }

  // ---- epilogue: C write (+bias) ----
  bfr_t* Cb = Cout + (size_t)bz * M * LL;
  int crow = m0 + wm * 128 + quad * 4;
  int ccol = n0 + wn * 64 + r16;
#pragma unroll
  for (int am = 0; am < 8; ++am) {
    int rbase = crow + (am >> 2) * 64 + (am & 3) * 16;
#pragma unroll
    for (int reg = 0; reg < 4; ++reg) {
      int row = rbase + reg;
      float bi = bias ? bias[row] : 0.f;
#pragma unroll
      for (int an = 0; an < 4; ++an) {
        int col = ccol + (an >> 1) * 32 + (an & 1) * 16;
        Cb[(size_t)row * LL + col] = f2bf(acc[am][an][reg] + bi);
      }
    }
  }
}

// --------- context partials via MFMA: ctx_p[bh][s][d][e], n split 8 ---------
__global__ __launch_bounds__(256) void context_mfma(
    const bfr_t* __restrict__ qkv, float* __restrict__ ctx_p,
    float* __restrict__ ksum_p) {
  __shared__ float red[4][4096];      // 64 KB: per-wave 64x64 partial
  int s = blockIdx.x, bh = blockIdx.y;
  int b = bh >> 3, h = bh & 7;
  int t = threadIdx.x, lane = t & 63, wid = t >> 6;
  int quad = lane >> 4, r = lane & 15;
  const bfr_t* kb = qkv + ((size_t)b * TC + 512 + h * 64) * LL;   // raw k rows
  const bfr_t* vb = qkv + ((size_t)b * TC + 1024 + h * 64) * LL;  // v rows
  int n_base = s * 512 + wid * 128;
  f32x4 acc[4][4] = {};
  float ps[4] = {};                    // per-lane exp-sum partials, row d=i*16+r
#pragma unroll
  for (int ks = 0; ks < 4; ++ks) {
    int n0 = n_base + ks * 32;
    short8 af[4], bf8[4];
#pragma unroll
    for (int i = 0; i < 4; ++i) {
      union { short s[8]; short8 v8; } uk;
      uk.v8 = *(const short8*)&kb[(size_t)(i * 16 + r) * LL + n0 + quad * 8];
#pragma unroll
      for (int jj = 0; jj < 8; ++jj) {
        float e = __expf(bf2f((bfr_t)uk.s[jj]));
        uk.s[jj] = (short)f2bf(e);
        ps[i] += e;
      }
      af[i] = uk.v8;
      bf8[i] = *(const short8*)&vb[(size_t)(i * 16 + r) * LL + n0 + quad * 8];
    }
#pragma unroll
    for (int i = 0; i < 4; ++i)
#pragma unroll
      for (int j = 0; j < 4; ++j)
        acc[i][j] = __builtin_amdgcn_mfma_f32_16x16x32_bf16(af[i], bf8[j],
                                                            acc[i][j], 0, 0, 0);
  }
  // ksum: reduce across the quad lanes holding the same row d
#pragma unroll
  for (int i = 0; i < 4; ++i) {
    ps[i] += __shfl_xor(ps[i], 16, 64);
    ps[i] += __shfl_xor(ps[i], 32, 64);
  }
  if (quad == 0) {
#pragma unroll
    for (int i = 0; i < 4; ++i) red[wid][i * 16 + r] = ps[i];
  }
  __syncthreads();
  if (t < 64)
    ksum_p[((size_t)bh * 8 + s) * 64 + t] =
        red[0][t] + red[1][t] + red[2][t] + red[3][t];
  __syncthreads();
  // each wave writes its 64x64 partial to its LDS quadrant, then block-sum
#pragma unroll
  for (int i = 0; i < 4; ++i)
#pragma unroll
    for (int j = 0; j < 4; ++j)
#pragma unroll
      for (int reg = 0; reg < 4; ++reg)
        red[wid][(i * 16 + quad * 4 + reg) * 64 + j * 16 + r] = acc[i][j][reg];
  __syncthreads();
  float* out = ctx_p + ((size_t)bh * 8 + s) * 4096;
#pragma unroll
  for (int u = 0; u < 16; ++u) {
    int idx = u * 256 + t;
    out[idx] = red[0][idx] + red[1][idx] + red[2][idx] + red[3][idx];
  }
}

// ------- reduce partials, apply 1/Z -> ctx_bf[bh][d][e] (bf16) --------------
__global__ __launch_bounds__(256) void context_reduce(
    const float* __restrict__ ctx_p, const float* __restrict__ ksum_p,
    bfr_t* __restrict__ ctx_bf) {
  __shared__ float zinv[64];
  int bh = blockIdx.x;
  int t = threadIdx.x;
  if (t < 64) {
    float s = 0.f;
#pragma unroll
    for (int s8 = 0; s8 < 8; ++s8) s += ksum_p[((size_t)bh * 8 + s8) * 64 + t];
    zinv[t] = 1.f / s;
  }
  __syncthreads();
#pragma unroll
  for (int i = 0; i < 16; ++i) {
    int idx = i * 256 + t;            // idx = d*64 + e
    int d = idx >> 6;
    float sum = 0.f;
#pragma unroll
    for (int s = 0; s < 8; ++s) sum += ctx_p[((size_t)bh * 8 + s) * 4096 + idx];
    ctx_bf[(size_t)bh * 4096 + idx] = f2bf(sum * zinv[d]);
  }
}

// --- fused q-softmax + apply: out_t[b][n][h*64+e] = softmax_d(q)^T ctx -----
__global__ __launch_bounds__(256) void apply_fused(
    const bfr_t* __restrict__ qkv, const bfr_t* __restrict__ ctx_bf,
    bfr_t* __restrict__ out_t) {
  int b = blockIdx.z, h = blockIdx.y;
  int t = threadIdx.x, lane = t & 63, wid = t >> 6;
  int quad = lane >> 4, r = lane & 15;
  int n0 = blockIdx.x * 256 + wid * 64;
  const bfr_t* qb = qkv + ((size_t)b * TC + h * 64) * LL;   // q rows [d][n]
  const bfr_t* cb = ctx_bf + (size_t)(b * HH + h) * 4096;   // [d][e]
  float v[4][16];
  float pm[4];
#pragma unroll
  for (int i = 0; i < 4; ++i) {
    pm[i] = -1e30f;
#pragma unroll
    for (int ks = 0; ks < 2; ++ks)
#pragma unroll
      for (int jj = 0; jj < 8; ++jj) {
        float q = bf2f(qb[(size_t)(ks * 32 + quad * 8 + jj) * LL + n0 + i * 16 + r]);
        v[i][ks * 8 + jj] = q;
        pm[i] = fmaxf(pm[i], q);
      }
  }
#pragma unroll
  for (int i = 0; i < 4; ++i) {
    pm[i] = fmaxf(pm[i], __shfl_xor(pm[i], 16, 64));
    pm[i] = fmaxf(pm[i], __shfl_xor(pm[i], 32, 64));
  }
  float psum[4];
#pragma unroll
  for (int i = 0; i < 4; ++i) {
    float s = 0.f;
#pragma unroll
    for (int u = 0; u < 16; ++u) { v[i][u] = __expf(v[i][u] - pm[i]); s += v[i][u]; }
    psum[i] = s;
  }
#pragma unroll
  for (int i = 0; i < 4; ++i) {
    psum[i] += __shfl_xor(psum[i], 16, 64);
    psum[i] += __shfl_xor(psum[i], 32, 64);
  }
  short8 af[2][4];
#pragma unroll
  for (int i = 0; i < 4; ++i) {
    float sc = SCALE_Q / psum[i];
#pragma unroll
    for (int ks = 0; ks < 2; ++ks) {
      union { short s[8]; short8 v8; } u;
#pragma unroll
      for (int jj = 0; jj < 8; ++jj) u.s[jj] = (short)f2bf(v[i][ks * 8 + jj] * sc);
      af[ks][i] = u.v8;
    }
  }
  short8 bfrag[2][4];
#pragma unroll
  for (int ks = 0; ks < 2; ++ks)
#pragma unroll
    for (int j = 0; j < 4; ++j) {
      union { short s[8]; short8 v8; } u;
#pragma unroll
      for (int jj = 0; jj < 8; ++jj)
        u.s[jj] = (short)cb[(ks * 32 + quad * 8 + jj) * 64 + j * 16 + r];
      bfrag[ks][j] = u.v8;
    }
  f32x4 acc[4][4] = {};
#pragma unroll
  for (int ks = 0; ks < 2; ++ks)
#pragma unroll
    for (int i = 0; i < 4; ++i)
#pragma unroll
      for (int j = 0; j < 4; ++j)
        acc[i][j] = __builtin_amdgcn_mfma_f32_16x16x32_bf16(af[ks][i], bfrag[ks][j],
                                                            acc[i][j], 0, 0, 0);
  bfr_t* dst = out_t + (size_t)b * LL * 512 + h * 64;
#pragma unroll
  for (int i = 0; i < 4; ++i)
#pragma unroll
    for (int reg = 0; reg < 4; ++reg) {
      int row = n0 + i * 16 + quad * 4 + reg;
#pragma unroll
      for (int j = 0; j < 4; ++j)
        dst[(size_t)row * 512 + j * 16 + r] = f2bf(acc[i][j][reg]);
    }
}

// ------------------- final rmsnorm over c + residual add --------------------
__global__ __launch_bounds__(256) void final_norm_res(
    const bfr_t* __restrict__ o, const float* __restrict__ g,
    const float* __restrict__ x, float* __restrict__ out) {
  __shared__ float red[4][64];
  __shared__ float invn[64];
  int b = blockIdx.y, l0 = blockIdx.x * 64;
  int t = threadIdx.x, ll = t & 63, cg = t >> 6;
  const bfr_t* ob = o + (size_t)b * CC * LL + l0 + ll;
  float ss = 0.f;
  for (int c = cg * 128; c < cg * 128 + 128; ++c) {
    float v = bf2f(ob[(size_t)c * LL]);
    ss += v * v;
  }
  red[cg][ll] = ss;
  __syncthreads();
  if (cg == 0) {
    float s = red[0][ll] + red[1][ll] + red[2][ll] + red[3][ll];
    invn[ll] = SQRT_C / fmaxf(sqrtf(s), 1e-12f);
  }
  __syncthreads();
  float iv = invn[ll];
  const float* xb = x + (size_t)b * CC * LL + l0 + ll;
  float* outb = out + (size_t)b * CC * LL + l0 + ll;
  for (int c = cg * 128; c < cg * 128 + 128; ++c) {
    float v = bf2f(ob[(size_t)c * LL]);
    outb[(size_t)c * LL] = v * g[c] * iv + xb[(size_t)c * LL];
  }
}

// ---------------------------------------------------------------------------
extern "C" void kernel_launch(void* const* d_in, const int* in_sizes, int n_in,
                              void* d_out, int out_size, void* d_ws,
                              size_t ws_size, hipStream_t stream) {
  const float* x     = (const float*)d_in[0];
  const float* g_in  = (const float*)d_in[1];
  const float* w_qkv = (const float*)d_in[2];
  const float* w_out = (const float*)d_in[3];
  const float* b_out = (const float*)d_in[4];
  const float* g_out = (const float*)d_in[5];
  float* out = (float*)d_out;

  // workspace layout (bytes)
  char* ws = (char*)d_ws;
  const size_t off_wqkv  = 0;                       // 1536*512*2 = 1,572,864
  const size_t off_wout  = 1572864;                 // 512*512*2  =   524,288
  const size_t off_ksump = 2097152;                 // 64*8*64*4  =   131,072
  const size_t off_ctx   = 2260992;                 // 64*64*64*2 =   524,288 (bf16)
  const size_t off_ctxp  = 3309568;                 // 64*8*4096*4 = 8,388,608
  const size_t off_xt    = 11698176;                // 32MB  (xn_t, later out_t)
  const size_t off_qkv   = 45252608;                // 96MB  (later o_bf)
  const size_t ws_need   = 145915904;
  if (ws_size < ws_need) return;   // insufficient scratch -> fail loudly

  bfr_t* wqkv_bf = (bfr_t*)(ws + off_wqkv);
  bfr_t* wout_bf = (bfr_t*)(ws + off_wout);
  float* ksum_p  = (float*)(ws + off_ksump);
  bfr_t* ctx_bf  = (bfr_t*)(ws + off_ctx);
  float* ctxp    = (float*)(ws + off_ctxp);
  bfr_t* xt      = (bfr_t*)(ws + off_xt);    // xn_t then out_t (disjoint lifetimes)
  bfr_t* qkv     = (bfr_t*)(ws + off_qkv);
  bfr_t* o_bf    = (bfr_t*)(ws + off_qkv);   // overwrites dead q/k/v after apply

  // 1. weights -> bf16 (single vectorized launch)
  conv_bf16_2<<<dim3((1536 * 512 + 512 * 512) / 8 / 256), 256, 0, stream>>>(
      w_qkv, wqkv_bf, 1536 * 512, w_out, wout_bf, 512 * 512);
  // 2. fused input rmsnorm + transpose -> bf16 xt
  fused_norm_transpose<<<dim3(LL / 64, BB), 256, 0, stream>>>(x, g_in, xt);
  // 3. qkv = W_qkv @ xn   (256^2 8-phase pipelined GEMM)
  gemm256<<<dim3(LL / 256, TC / 256, BB), 512, 0, stream>>>(wqkv_bf, xt, qkv, nullptr, TC);
  // 4. context = exp(k) v^T via MFMA (exp + ksum inline), reduce + 1/Z -> bf16
  context_mfma<<<dim3(8, BB * HH), 256, 0, stream>>>(qkv, ctxp, ksum_p);
  context_reduce<<<dim3(BB * HH), 256, 0, stream>>>(ctxp, ksum_p, ctx_bf);
  // 5. fused q-softmax + apply -> out_t (xn_t now dead)
  apply_fused<<<dim3(LL / 256, HH, BB), 256, 0, stream>>>(qkv, ctx_bf, xt);
  // 6. o = W_out @ out + b_out   (qkv fully dead now)
  gemm256<<<dim3(LL / 256, CC / 256, BB), 512, 0, stream>>>(wout_bf, xt, o_bf, b_out, CC);
  // 7. final rmsnorm + residual -> fp32 out
  final_norm_res<<<dim3(LL / 64, BB), 256, 0, stream>>>(o_bf, g_out, x, out);
}

// Round 2
// 288.843 us; speedup vs baseline: 1.0693x; 1.0180x over previous
//
#include <hip/hip_runtime.h>

// ---------------------------------------------------------------------------
// LinearAttention (b=8, c=512, l=4096, heads=8, dim_head=64)
//   xn = rmsnorm_ch(x, g_in); qkv = W_qkv @ xn
//   q = softmax_d(q)*scale; k = softmax_l(k)
//   ctx = k v^T; out = ctx^T q; o = rmsnorm_ch(W_out @ out + b_out) + x
// GEMMs: 256x256 8-phase pipelined schedule (T2 swizzle + T3/T4 counted
// vmcnt + T5 setprio), 8 waves, 128 KB LDS double-buffer, 16x16x32 MFMA.
// Fragment loads are inline-asm ds_read_b128 so the compiler's LDS-DMA
// alias tracking cannot insert vmcnt(0) drains before them (the round-1
// pipeline was defeated by exactly that). Counted vmcnt(6) per K-tile.
// ---------------------------------------------------------------------------

#define BB 8
#define CC 512
#define LL 4096
#define HH 8
#define DH 64
#define TC 1536

__device__ __constant__ const float SQRT_C = 22.62741699796952f;   // sqrt(512)
#define SCALE_Q 0.125f                                             // 64^-0.5

typedef unsigned short bfr_t;
typedef __attribute__((ext_vector_type(8))) short short8;
typedef __attribute__((ext_vector_type(4))) float f32x4;
typedef __attribute__((ext_vector_type(16))) float f32x16;

__device__ __forceinline__ float bf2f(bfr_t v) {
  union { unsigned u; float f; } c; c.u = ((unsigned)v) << 16; return c.f;
}
__device__ __forceinline__ bfr_t f2bf(float f) {
  union { float f; unsigned u; } c; c.f = f;
  unsigned u = c.u + 0x7fffu + ((c.u >> 16) & 1u);   // RNE, ignores NaN edge
  return (bfr_t)(u >> 16);
}

__device__ __forceinline__ void load_lds16(const bfr_t* g, short* l) {
  __builtin_amdgcn_global_load_lds(
      (const __attribute__((address_space(1))) void*)g,
      (__attribute__((address_space(3))) void*)l, 16, 0, 0);
}

// -------- f32 -> bf16 convert (both weights, vectorized x8, 1 launch) ------
__global__ __launch_bounds__(256) void conv_bf16_2(
    const float* __restrict__ in1, bfr_t* __restrict__ o1, int n1,
    const float* __restrict__ in2, bfr_t* __restrict__ o2, int n2) {
  int i8 = (blockIdx.x * 256 + threadIdx.x) * 8;
  const float* src;
  bfr_t* dst;
  if (i8 < n1) { src = in1 + i8; dst = o1 + i8; }
  else {
    int j8 = i8 - n1;
    if (j8 >= n2) return;
    src = in2 + j8; dst = o2 + j8;
  }
  f32x4 a = *(const f32x4*)src;
  f32x4 b = *(const f32x4*)(src + 4);
  union { short s[8]; f32x4 v; } pk;
#pragma unroll
  for (int u = 0; u < 4; ++u) { pk.s[u] = (short)f2bf(a[u]); pk.s[u + 4] = (short)f2bf(b[u]); }
  *(f32x4*)dst = pk.v;
}

// ------ fused channel-RMSNorm + transpose: x[b][c][l] -> xt[b][l][c] -------
__global__ __launch_bounds__(256) void fused_norm_transpose(
    const float* __restrict__ x, const float* __restrict__ g,
    bfr_t* __restrict__ xt) {
  __shared__ float tile[64][65];
  __shared__ float red[4][64];
  __shared__ float invn_s[64];
  int b = blockIdx.y, l0 = blockIdx.x * 64;
  int t = threadIdx.x, ll = t & 63, cg = t >> 6;
  const float* xb = x + (size_t)b * CC * LL + l0;
  float vals[8][16];
  float ss = 0.f;
#pragma unroll
  for (int ch = 0; ch < 8; ++ch) {
    int c0 = ch * 64;
#pragma unroll
    for (int i = 0; i < 16; ++i) {
      int c = i * 4 + cg;                       // chunk-local channel
      float v = xb[(size_t)(c0 + c) * LL + ll];
      vals[ch][i] = v;
      ss += v * v;
    }
  }
  red[cg][ll] = ss;
  __syncthreads();
  if (cg == 0) {
    float s = red[0][ll] + red[1][ll] + red[2][ll] + red[3][ll];
    invn_s[ll] = SQRT_C / fmaxf(sqrtf(s), 1e-12f);
  }
  __syncthreads();
  int lw = t >> 2, ccw = (t & 3) * 16;
  float iv = invn_s[lw];
#pragma unroll
  for (int ch = 0; ch < 8; ++ch) {
    int c0 = ch * 64;
#pragma unroll
    for (int i = 0; i < 16; ++i) tile[i * 4 + cg][ll] = vals[ch][i];
    __syncthreads();
    union { short s[16]; f32x4 v[2]; } pk;
#pragma unroll
    for (int u = 0; u < 16; ++u) {
      int c = ccw + u;
      pk.s[u] = (short)f2bf(tile[c][lw] * g[c0 + c] * iv);
    }
    bfr_t* dst = xt + ((size_t)b * LL + l0 + lw) * CC + c0 + ccw;
    *(f32x4*)dst = pk.v[0];
    *(f32x4*)(dst + 8) = pk.v[1];
    __syncthreads();
  }
}

// ----------------------- 256x256 8-phase bf16 GEMM -------------------------
// C[b][m][n] = sum_k A[m][k] * Bt[b][n][k] (+ bias[m]); A:[M][512], Bt:[B][L][512]
// 8 waves (2M x 4N), per-wave 128x64 out. LDS: 2 dbuf x 2 half x [128][64]
// per operand = 128 KB. Per K-tile: 4 phases, each {asm ds_read, stage
// half-tile, barrier, lgkmcnt(0), setprio(1), 16 MFMA, setprio(0), barrier};
// one counted vmcnt(6) per K-tile (never 0 mid-loop). 16B XOR swizzle.
// grid (L/256, M/256, B), block 512.
#define NT 8                                      // K-tiles (K=512, BK=64)

__device__ __forceinline__ void stage_half(const bfr_t* g, short* l, int wid) {
  // g is lane-adjusted (soff folded in); wave stages 2 KB of the 16 KB half
  load_lds16(g + (size_t)wid * 8192,        l + wid * 1024);
  load_lds16(g + (size_t)wid * 8192 + 4096, l + wid * 1024 + 512);
}

#define CFENCE asm volatile("" ::: "memory")
#define PHASE_MID()                                          \
  do { CFENCE; __builtin_amdgcn_s_barrier();                 \
       asm volatile("s_waitcnt lgkmcnt(0)" ::: "memory");    \
       __builtin_amdgcn_sched_barrier(0); } while (0)
#define PHASE_END()                                          \
  do { CFENCE; __builtin_amdgcn_s_barrier(); CFENCE; } while (0)

// inline-asm ds_read_b128 with literal offset -- invisible to the compiler's
// LDS-DMA alias tracking (prevents inserted s_waitcnt vmcnt(0) drains).
#define DSR(dst, addr, lit) \
  asm volatile("ds_read_b128 %0, %1 offset:" lit : "=v"(dst) : "v"(addr))

#define LOAD_A0() do {                       \
    DSR(a_reg[0], aAs0, "0");                \
    DSR(a_reg[1], aAs1, "0");                \
    DSR(a_reg[2], aAs0, "2048");             \
    DSR(a_reg[3], aAs1, "2048");             \
    DSR(a_reg[4], aAs0, "4096");             \
    DSR(a_reg[5], aAs1, "4096");             \
    DSR(a_reg[6], aAs0, "6144");             \
    DSR(a_reg[7], aAs1, "6144"); } while (0)

#define LOAD_A1() do {                       \
    DSR(a_reg[0], aAs0, "8192");             \
    DSR(a_reg[1], aAs1, "8192");             \
    DSR(a_reg[2], aAs0, "10240");            \
    DSR(a_reg[3], aAs1, "10240");            \
    DSR(a_reg[4], aAs0, "12288");            \
    DSR(a_reg[5], aAs1, "12288");            \
    DSR(a_reg[6], aAs0, "14336");            \
    DSR(a_reg[7], aAs1, "14336"); } while (0)

#define LOAD_B0() do {                       \
    DSR(b_reg[0][0], bBs0, "0");             \
    DSR(b_reg[0][1], bBs1, "0");             \
    DSR(b_reg[0][2], bBs0, "2048");          \
    DSR(b_reg[0][3], bBs1, "2048"); } while (0)

#define LOAD_B1() do {                       \
    DSR(b_reg[1][0], bBs0, "4096");          \
    DSR(b_reg[1][1], bBs1, "4096");          \
    DSR(b_reg[1][2], bBs0, "6144");          \
    DSR(b_reg[1][3], bBs1, "6144"); } while (0)

#define MMA_Q(QM, QN) do {                                                   \
    __builtin_amdgcn_s_setprio(1);                                           \
    _Pragma("unroll") for (int i_ = 0; i_ < 4; ++i_) {                       \
      _Pragma("unroll") for (int j_ = 0; j_ < 2; ++j_) {                     \
        acc[(QM) * 4 + i_][(QN) * 2 + j_] =                                  \
            __builtin_amdgcn_mfma_f32_16x16x32_bf16(                         \
                a_reg[i_ * 2 + 0], b_reg[QN][j_ * 2 + 0],                    \
                acc[(QM) * 4 + i_][(QN) * 2 + j_], 0, 0, 0);                 \
        acc[(QM) * 4 + i_][(QN) * 2 + j_] =                                  \
            __builtin_amdgcn_mfma_f32_16x16x32_bf16(                         \
                a_reg[i_ * 2 + 1], b_reg[QN][j_ * 2 + 1],                    \
                acc[(QM) * 4 + i_][(QN) * 2 + j_], 0, 0, 0);                 \
      } }                                                                    \
    __builtin_amdgcn_s_setprio(0); } while (0)

__global__ __launch_bounds__(512, 2) void gemm256(
    const bfr_t* __restrict__ A, const bfr_t* __restrict__ Bt,
    bfr_t* __restrict__ Cout, const float* __restrict__ bias, int M) {
  __shared__ short lds[65536];          // 128 KB
  short* As = lds;                      // [2 buf][2 half][128][64]
  short* Bs = lds + 32768;
  int bz = blockIdx.z;
  int m0 = blockIdx.y * 256, n0 = blockIdx.x * 256;
  int t = threadIdx.x, lane = t & 63, wid = t >> 6;
  int quad = lane >> 4, r16 = lane & 15;
  int wm = wid >> 2, wn = wid & 3;
  // staging source offset: row (lane>>3), pre-swizzled granule (l&7)^(l>>3)
  int soff = (lane >> 3) * 512 + (((lane & 7) ^ (lane >> 3)) * 8);
  // ds_read swizzled k-granule slots (shorts): slot = gran^  (row&7), x8
  int slot0 = (quad ^ (lane & 7)) * 8;          // ks=0
  int slot1 = ((4 + quad) ^ (lane & 7)) * 8;    // ks=1

  // LDS byte addresses for the asm ds_reads (per buf x per slot)
  unsigned lb = (unsigned)(uintptr_t)(__attribute__((address_space(3))) short*)lds;
  unsigned aA0_0 = lb + (unsigned)(wm * 16384 + r16 * 128 + slot0 * 2);
  unsigned aA0_1 = lb + (unsigned)(wm * 16384 + r16 * 128 + slot1 * 2);
  unsigned aA1_0 = aA0_0 + 32768u;
  unsigned aA1_1 = aA0_1 + 32768u;
  unsigned bbase = 65536u + (unsigned)((wn >> 1) * 16384 + ((wn & 1) * 64 + r16) * 128);
  unsigned bB0_0 = lb + bbase + (unsigned)(slot0 * 2);
  unsigned bB0_1 = lb + bbase + (unsigned)(slot1 * 2);
  unsigned bB1_0 = bB0_0 + 32768u;
  unsigned bB1_1 = bB0_1 + 32768u;

  const bfr_t* pA0 = A + (size_t)m0 * 512 + soff;
  const bfr_t* pA1 = pA0 + (size_t)128 * 512;
  const bfr_t* pB0 = Bt + (size_t)bz * LL * 512 + (size_t)n0 * 512 + soff;
  const bfr_t* pB1 = pB0 + (size_t)128 * 512;

  f32x4 acc[8][4] = {};
  short8 a_reg[8];
  short8 b_reg[2][4];

  // ---- prologue: stage K-tiles 0 and 1 (16 loads/wave) ----
  stage_half(pA0, As, wid);                    // t0 A0 -> buf0
  stage_half(pA1, As + 8192, wid);             // t0 A1
  stage_half(pB0, Bs, wid);                    // t0 B0
  stage_half(pB1, Bs + 8192, wid);             // t0 B1
  stage_half(pA0 + 64, As + 16384, wid);       // t1 A0 -> buf1
  stage_half(pA1 + 64, As + 24576, wid);       // t1 A1
  stage_half(pB0 + 64, Bs + 16384, wid);       // t1 B0
  stage_half(pB1 + 64, Bs + 24576, wid);       // t1 B1
  asm volatile("s_waitcnt vmcnt(8)" ::: "memory");   // tile 0 landed
  CFENCE; __builtin_amdgcn_s_barrier(); CFENCE;

#pragma unroll
  for (int kt = 0; kt < NT; ++kt) {
    const int buf = kt & 1;
    const unsigned aAs0 = buf ? aA1_0 : aA0_0;
    const unsigned aAs1 = buf ? aA1_1 : aA0_1;
    const unsigned bBs0 = buf ? bB1_0 : bB0_0;
    const unsigned bBs1 = buf ? bB1_1 : bB0_1;
    // ---- phase 1: quadrant (qm=0, qn=0); stage A1(kt+1) -> buf^1 ----
    LOAD_A0();
    LOAD_B0();
    if (kt >= 1 && kt <= NT - 2)
      stage_half(pA1 + (kt + 1) * 64, As + (((kt + 1) & 1) * 2 + 1) * 8192, wid);
    PHASE_MID();
    MMA_Q(0, 0);
    PHASE_END();
    // ---- phase 2: (0,1) ----
    LOAD_B1();
    PHASE_MID();
    MMA_Q(0, 1);
    PHASE_END();
    // ---- phase 3: (1,1); B halves of buf fully read -> stage B0(kt+2) ----
    LOAD_A1();
    if (kt <= NT - 3)
      stage_half(pB0 + (kt + 2) * 64, Bs + (buf * 2) * 8192, wid);
    PHASE_MID();
    MMA_Q(1, 1);
    PHASE_END();
    // ---- phase 4: (1,0); A halves fully read -> stage B1,A0(kt+2) ----
    if (kt <= NT - 3) {
      stage_half(pB1 + (kt + 2) * 64, Bs + (buf * 2 + 1) * 8192, wid);
      stage_half(pA0 + (kt + 2) * 64, As + (buf * 2) * 8192, wid);
    }
    PHASE_MID();
    MMA_Q(1, 0);
    __builtin_amdgcn_sched_barrier(0);
    // counted vmcnt: next tile's data landed, 3 half-tiles stay in flight
    if (kt <= NT - 3)      { asm volatile("s_waitcnt vmcnt(6)" ::: "memory"); }
    else if (kt == NT - 2) { asm volatile("s_waitcnt vmcnt(0)" ::: "memory"); }
    CFENCE; __builtin_amdgcn_s_barrier(); CFENCE;
  }

  // ---- epilogue: C write (+bias) ----
  bfr_t* Cb = Cout + (size_t)bz * M * LL;
  int crow = m0 + wm * 128 + quad * 4;
  int ccol = n0 + wn * 64 + r16;
#pragma unroll
  for (int am = 0; am < 8; ++am) {
    int rbase = crow + (am >> 2) * 64 + (am & 3) * 16;
#pragma unroll
    for (int reg = 0; reg < 4; ++reg) {
      int row = rbase + reg;
      float bi = bias ? bias[row] : 0.f;
#pragma unroll
      for (int an = 0; an < 4; ++an) {
        int col = ccol + (an >> 1) * 32 + (an & 1) * 16;
        Cb[(size_t)row * LL + col] = f2bf(acc[am][an][reg] + bi);
      }
    }
  }
}

// --------- context partials via MFMA: ctx_p[bh][s][d][e], n split 8 ---------
__global__ __launch_bounds__(256) void context_mfma(
    const bfr_t* __restrict__ qkv, float* __restrict__ ctx_p,
    float* __restrict__ ksum_p) {
  __shared__ float red[4][4096];      // 64 KB: per-wave 64x64 partial
  int s = blockIdx.x, bh = blockIdx.y;
  int b = bh >> 3, h = bh & 7;
  int t = threadIdx.x, lane = t & 63, wid = t >> 6;
  int quad = lane >> 4, r = lane & 15;
  const bfr_t* kb = qkv + ((size_t)b * TC + 512 + h * 64) * LL;   // raw k rows
  const bfr_t* vb = qkv + ((size_t)b * TC + 1024 + h * 64) * LL;  // v rows
  int n_base = s * 512 + wid * 128;
  f32x4 acc[4][4] = {};
  float ps[4] = {};                    // per-lane exp-sum partials, row d=i*16+r
#pragma unroll
  for (int ks = 0; ks < 4; ++ks) {
    int n0 = n_base + ks * 32;
    short8 af[4], bf8[4];
#pragma unroll
    for (int i = 0; i < 4; ++i) {
      union { short s[8]; short8 v8; } uk;
      uk.v8 = *(const short8*)&kb[(size_t)(i * 16 + r) * LL + n0 + quad * 8];
#pragma unroll
      for (int jj = 0; jj < 8; ++jj) {
        float e = __expf(bf2f((bfr_t)uk.s[jj]));
        uk.s[jj] = (short)f2bf(e);
        ps[i] += e;
      }
      af[i] = uk.v8;
      bf8[i] = *(const short8*)&vb[(size_t)(i * 16 + r) * LL + n0 + quad * 8];
    }
#pragma unroll
    for (int i = 0; i < 4; ++i)
#pragma unroll
      for (int j = 0; j < 4; ++j)
        acc[i][j] = __builtin_amdgcn_mfma_f32_16x16x32_bf16(af[i], bf8[j],
                                                            acc[i][j], 0, 0, 0);
  }
  // ksum: reduce across the quad lanes holding the same row d
#pragma unroll
  for (int i = 0; i < 4; ++i) {
    ps[i] += __shfl_xor(ps[i], 16, 64);
    ps[i] += __shfl_xor(ps[i], 32, 64);
  }
  if (quad == 0) {
#pragma unroll
    for (int i = 0; i < 4; ++i) red[wid][i * 16 + r] = ps[i];
  }
  __syncthreads();
  if (t < 64)
    ksum_p[((size_t)bh * 8 + s) * 64 + t] =
        red[0][t] + red[1][t] + red[2][t] + red[3][t];
  __syncthreads();
  // each wave writes its 64x64 partial to its LDS quadrant, then block-sum
#pragma unroll
  for (int i = 0; i < 4; ++i)
#pragma unroll
    for (int j = 0; j < 4; ++j)
#pragma unroll
      for (int reg = 0; reg < 4; ++reg)
        red[wid][(i * 16 + quad * 4 + reg) * 64 + j * 16 + r] = acc[i][j][reg];
  __syncthreads();
  float* out = ctx_p + ((size_t)bh * 8 + s) * 4096;
#pragma unroll
  for (int u = 0; u < 16; ++u) {
    int idx = u * 256 + t;
    out[idx] = red[0][idx] + red[1][idx] + red[2][idx] + red[3][idx];
  }
}

// ------- reduce partials, apply 1/Z -> ctx_bf[bh][d][e] (bf16) --------------
__global__ __launch_bounds__(256) void context_reduce(
    const float* __restrict__ ctx_p, const float* __restrict__ ksum_p,
    bfr_t* __restrict__ ctx_bf) {
  __shared__ float zinv[64];
  int bh = blockIdx.x;
  int t = threadIdx.x;
  if (t < 64) {
    float s = 0.f;
#pragma unroll
    for (int s8 = 0; s8 < 8; ++s8) s += ksum_p[((size_t)bh * 8 + s8) * 64 + t];
    zinv[t] = 1.f / s;
  }
  __syncthreads();
#pragma unroll
  for (int i = 0; i < 16; ++i) {
    int idx = i * 256 + t;            // idx = d*64 + e
    int d = idx >> 6;
    float sum = 0.f;
#pragma unroll
    for (int s = 0; s < 8; ++s) sum += ctx_p[((size_t)bh * 8 + s) * 4096 + idx];
    ctx_bf[(size_t)bh * 4096 + idx] = f2bf(sum * zinv[d]);
  }
}

// --- fused q-softmax + apply: out_t[b][n][h*64+e] = softmax_d(q)^T ctx -----
__global__ __launch_bounds__(256) void apply_fused(
    const bfr_t* __restrict__ qkv, const bfr_t* __restrict__ ctx_bf,
    bfr_t* __restrict__ out_t) {
  int b = blockIdx.z, h = blockIdx.y;
  int t = threadIdx.x, lane = t & 63, wid = t >> 6;
  int quad = lane >> 4, r = lane & 15;
  int n0 = blockIdx.x * 256 + wid * 64;
  const bfr_t* qb = qkv + ((size_t)b * TC + h * 64) * LL;   // q rows [d][n]
  const bfr_t* cb = ctx_bf + (size_t)(b * HH + h) * 4096;   // [d][e]
  float v[4][16];
  float pm[4];
#pragma unroll
  for (int i = 0; i < 4; ++i) {
    pm[i] = -1e30f;
#pragma unroll
    for (int ks = 0; ks < 2; ++ks)
#pragma unroll
      for (int jj = 0; jj < 8; ++jj) {
        float q = bf2f(qb[(size_t)(ks * 32 + quad * 8 + jj) * LL + n0 + i * 16 + r]);
        v[i][ks * 8 + jj] = q;
        pm[i] = fmaxf(pm[i], q);
      }
  }
#pragma unroll
  for (int i = 0; i < 4; ++i) {
    pm[i] = fmaxf(pm[i], __shfl_xor(pm[i], 16, 64));
    pm[i] = fmaxf(pm[i], __shfl_xor(pm[i], 32, 64));
  }
  float psum[4];
#pragma unroll
  for (int i = 0; i < 4; ++i) {
    float s = 0.f;
#pragma unroll
    for (int u = 0; u < 16; ++u) { v[i][u] = __expf(v[i][u] - pm[i]); s += v[i][u]; }
    psum[i] = s;
  }
#pragma unroll
  for (int i = 0; i < 4; ++i) {
    psum[i] += __shfl_xor(psum[i], 16, 64);
    psum[i] += __shfl_xor(psum[i], 32, 64);
  }
  short8 af[2][4];
#pragma unroll
  for (int i = 0; i < 4; ++i) {
    float sc = SCALE_Q / psum[i];
#pragma unroll
    for (int ks = 0; ks < 2; ++ks) {
      union { short s[8]; short8 v8; } u;
#pragma unroll
      for (int jj = 0; jj < 8; ++jj) u.s[jj] = (short)f2bf(v[i][ks * 8 + jj] * sc);
      af[ks][i] = u.v8;
    }
  }
  short8 bfrag[2][4];
#pragma unroll
  for (int ks = 0; ks < 2; ++ks)
#pragma unroll
    for (int j = 0; j < 4; ++j) {
      union { short s[8]; short8 v8; } u;
#pragma unroll
      for (int jj = 0; jj < 8; ++jj)
        u.s[jj] = (short)cb[(ks * 32 + quad * 8 + jj) * 64 + j * 16 + r];
      bfrag[ks][j] = u.v8;
    }
  f32x4 acc[4][4] = {};
#pragma unroll
  for (int ks = 0; ks < 2; ++ks)
#pragma unroll
    for (int i = 0; i < 4; ++i)
#pragma unroll
      for (int j = 0; j < 4; ++j)
        acc[i][j] = __builtin_amdgcn_mfma_f32_16x16x32_bf16(af[ks][i], bfrag[ks][j],
                                                            acc[i][j], 0, 0, 0);
  bfr_t* dst = out_t + (size_t)b * LL * 512 + h * 64;
#pragma unroll
  for (int i = 0; i < 4; ++i)
#pragma unroll
    for (int reg = 0; reg < 4; ++reg) {
      int row = n0 + i * 16 + quad * 4 + reg;
#pragma unroll
      for (int j = 0; j < 4; ++j)
        dst[(size_t)row * 512 + j * 16 + r] = f2bf(acc[i][j][reg]);
    }
}

// ------------------- final rmsnorm over c + residual add --------------------
__global__ __launch_bounds__(256) void final_norm_res(
    const bfr_t* __restrict__ o, const float* __restrict__ g,
    const float* __restrict__ x, float* __restrict__ out) {
  __shared__ float red[4][64];
  __shared__ float invn[64];
  int b = blockIdx.y, l0 = blockIdx.x * 64;
  int t = threadIdx.x, ll = t & 63, cg = t >> 6;
  const bfr_t* ob = o + (size_t)b * CC * LL + l0 + ll;
  float ss = 0.f;
  for (int c = cg * 128; c < cg * 128 + 128; ++c) {
    float v = bf2f(ob[(size_t)c * LL]);
    ss += v * v;
  }
  red[cg][ll] = ss;
  __syncthreads();
  if (cg == 0) {
    float s = red[0][ll] + red[1][ll] + red[2][ll] + red[3][ll];
    invn[ll] = SQRT_C / fmaxf(sqrtf(s), 1e-12f);
  }
  __syncthreads();
  float iv = invn[ll];
  const float* xb = x + (size_t)b * CC * LL + l0 + ll;
  float* outb = out + (size_t)b * CC * LL + l0 + ll;
  for (int c = cg * 128; c < cg * 128 + 128; ++c) {
    float v = bf2f(ob[(size_t)c * LL]);
    outb[(size_t)c * LL] = v * g[c] * iv + xb[(size_t)c * LL];
  }
}

// ---------------------------------------------------------------------------
extern "C" void kernel_launch(void* const* d_in, const int* in_sizes, int n_in,
                              void* d_out, int out_size, void* d_ws,
                              size_t ws_size, hipStream_t stream) {
  const float* x     = (const float*)d_in[0];
  const float* g_in  = (const float*)d_in[1];
  const float* w_qkv = (const float*)d_in[2];
  const float* w_out = (const float*)d_in[3];
  const float* b_out = (const float*)d_in[4];
  const float* g_out = (const float*)d_in[5];
  float* out = (float*)d_out;

  // workspace layout (bytes)
  char* ws = (char*)d_ws;
  const size_t off_wqkv  = 0;                       // 1536*512*2 = 1,572,864
  const size_t off_wout  = 1572864;                 // 512*512*2  =   524,288
  const size_t off_ksump = 2097152;                 // 64*8*64*4  =   131,072
  const size_t off_ctx   = 2260992;                 // 64*64*64*2 =   524,288 (bf16)
  const size_t off_ctxp  = 3309568;                 // 64*8*4096*4 = 8,388,608
  const size_t off_xt    = 11698176;                // 32MB  (xn_t, later out_t)
  const size_t off_qkv   = 45252608;                // 96MB  (later o_bf)
  const size_t ws_need   = 145915904;
  if (ws_size < ws_need) return;   // insufficient scratch -> fail loudly

  bfr_t* wqkv_bf = (bfr_t*)(ws + off_wqkv);
  bfr_t* wout_bf = (bfr_t*)(ws + off_wout);
  float* ksum_p  = (float*)(ws + off_ksump);
  bfr_t* ctx_bf  = (bfr_t*)(ws + off_ctx);
  float* ctxp    = (float*)(ws + off_ctxp);
  bfr_t* xt      = (bfr_t*)(ws + off_xt);    // xn_t then out_t (disjoint lifetimes)
  bfr_t* qkv     = (bfr_t*)(ws + off_qkv);
  bfr_t* o_bf    = (bfr_t*)(ws + off_qkv);   // overwrites dead q/k/v after apply

  // 1. weights -> bf16 (single vectorized launch)
  conv_bf16_2<<<dim3((1536 * 512 + 512 * 512) / 8 / 256), 256, 0, stream>>>(
      w_qkv, wqkv_bf, 1536 * 512, w_out, wout_bf, 512 * 512);
  // 2. fused input rmsnorm + transpose -> bf16 xt
  fused_norm_transpose<<<dim3(LL / 64, BB), 256, 0, stream>>>(x, g_in, xt);
  // 3. qkv = W_qkv @ xn   (256^2 8-phase pipelined GEMM, asm ds_read)
  gemm256<<<dim3(LL / 256, TC / 256, BB), 512, 0, stream>>>(wqkv_bf, xt, qkv, nullptr, TC);
  // 4. context = exp(k) v^T via MFMA (exp + ksum inline), reduce + 1/Z -> bf16
  context_mfma<<<dim3(8, BB * HH), 256, 0, stream>>>(qkv, ctxp, ksum_p);
  context_reduce<<<dim3(BB * HH), 256, 0, stream>>>(ctxp, ksum_p, ctx_bf);
  // 5. fused q-softmax + apply -> out_t (xn_t now dead)
  apply_fused<<<dim3(LL / 256, HH, BB), 256, 0, stream>>>(qkv, ctx_bf, xt);
  // 6. o = W_out @ out + b_out   (qkv fully dead now)
  gemm256<<<dim3(LL / 256, CC / 256, BB), 512, 0, stream>>>(wout_bf, xt, o_bf, b_out, CC);
  // 7. final rmsnorm + residual -> fp32 out
  final_norm_res<<<dim3(LL / 64, BB), 256, 0, stream>>>(o_bf, g_out, x, out);
}

// Round 3
// 286.175 us; speedup vs baseline: 1.0793x; 1.0093x over previous
//
#include <hip/hip_runtime.h>

// ---------------------------------------------------------------------------
// LinearAttention (b=8, c=512, l=4096, heads=8, dim_head=64)
//   xn = rmsnorm_ch(x, g_in); qkv = W_qkv @ xn
//   q = softmax_d(q)*scale; k = softmax_l(k)
//   ctx = k v^T; out = ctx^T q; o = rmsnorm_ch(W_out @ out + b_out) + x
// GEMMs: 256x256 8-phase pipelined schedule (T2 swizzle + T3/T4 counted
// vmcnt + T5 setprio), 8 waves, 128 KB LDS double-buffer, 16x16x32 MFMA.
// Round 3: bijective XCD-chunked block swizzle (y-fastest) so panel-sharing
// blocks co-reside per XCD -- staging served from L2 instead of a saturated
// L3 path (round-2 counters: 393 MB staging @ 5.5 TB/s, only 39 MB HBM).
// ---------------------------------------------------------------------------

#define BB 8
#define CC 512
#define LL 4096
#define HH 8
#define DH 64
#define TC 1536

__device__ __constant__ const float SQRT_C = 22.62741699796952f;   // sqrt(512)
#define SCALE_Q 0.125f                                             // 64^-0.5

typedef unsigned short bfr_t;
typedef __attribute__((ext_vector_type(8))) short short8;
typedef __attribute__((ext_vector_type(4))) float f32x4;
typedef __attribute__((ext_vector_type(16))) float f32x16;

__device__ __forceinline__ float bf2f(bfr_t v) {
  union { unsigned u; float f; } c; c.u = ((unsigned)v) << 16; return c.f;
}
__device__ __forceinline__ bfr_t f2bf(float f) {
  union { float f; unsigned u; } c; c.f = f;
  unsigned u = c.u + 0x7fffu + ((c.u >> 16) & 1u);   // RNE, ignores NaN edge
  return (bfr_t)(u >> 16);
}

__device__ __forceinline__ void load_lds16(const bfr_t* g, short* l) {
  __builtin_amdgcn_global_load_lds(
      (const __attribute__((address_space(1))) void*)g,
      (__attribute__((address_space(3))) void*)l, 16, 0, 0);
}

// -------- f32 -> bf16 convert (both weights, vectorized x8, 1 launch) ------
__global__ __launch_bounds__(256) void conv_bf16_2(
    const float* __restrict__ in1, bfr_t* __restrict__ o1, int n1,
    const float* __restrict__ in2, bfr_t* __restrict__ o2, int n2) {
  int i8 = (blockIdx.x * 256 + threadIdx.x) * 8;
  const float* src;
  bfr_t* dst;
  if (i8 < n1) { src = in1 + i8; dst = o1 + i8; }
  else {
    int j8 = i8 - n1;
    if (j8 >= n2) return;
    src = in2 + j8; dst = o2 + j8;
  }
  f32x4 a = *(const f32x4*)src;
  f32x4 b = *(const f32x4*)(src + 4);
  union { short s[8]; f32x4 v; } pk;
#pragma unroll
  for (int u = 0; u < 4; ++u) { pk.s[u] = (short)f2bf(a[u]); pk.s[u + 4] = (short)f2bf(b[u]); }
  *(f32x4*)dst = pk.v;
}

// ------ fused channel-RMSNorm + transpose: x[b][c][l] -> xt[b][l][c] -------
__global__ __launch_bounds__(256) void fused_norm_transpose(
    const float* __restrict__ x, const float* __restrict__ g,
    bfr_t* __restrict__ xt) {
  __shared__ float tile[64][65];
  __shared__ float red[4][64];
  __shared__ float invn_s[64];
  int b = blockIdx.y, l0 = blockIdx.x * 64;
  int t = threadIdx.x, ll = t & 63, cg = t >> 6;
  const float* xb = x + (size_t)b * CC * LL + l0;
  float vals[8][16];
  float ss = 0.f;
#pragma unroll
  for (int ch = 0; ch < 8; ++ch) {
    int c0 = ch * 64;
#pragma unroll
    for (int i = 0; i < 16; ++i) {
      int c = i * 4 + cg;                       // chunk-local channel
      float v = xb[(size_t)(c0 + c) * LL + ll];
      vals[ch][i] = v;
      ss += v * v;
    }
  }
  red[cg][ll] = ss;
  __syncthreads();
  if (cg == 0) {
    float s = red[0][ll] + red[1][ll] + red[2][ll] + red[3][ll];
    invn_s[ll] = SQRT_C / fmaxf(sqrtf(s), 1e-12f);
  }
  __syncthreads();
  int lw = t >> 2, ccw = (t & 3) * 16;
  float iv = invn_s[lw];
#pragma unroll
  for (int ch = 0; ch < 8; ++ch) {
    int c0 = ch * 64;
#pragma unroll
    for (int i = 0; i < 16; ++i) tile[i * 4 + cg][ll] = vals[ch][i];
    __syncthreads();
    union { short s[16]; f32x4 v[2]; } pk;
#pragma unroll
    for (int u = 0; u < 16; ++u) {
      int c = ccw + u;
      pk.s[u] = (short)f2bf(tile[c][lw] * g[c0 + c] * iv);
    }
    bfr_t* dst = xt + ((size_t)b * LL + l0 + lw) * CC + c0 + ccw;
    *(f32x4*)dst = pk.v[0];
    *(f32x4*)(dst + 8) = pk.v[1];
    __syncthreads();
  }
}

// ----------------------- 256x256 8-phase bf16 GEMM -------------------------
// C[b][m][n] = sum_k A[m][k] * Bt[b][n][k] (+ bias[m]); A:[M][512], Bt:[B][L][512]
// 8 waves (2M x 4N), per-wave 128x64 out. LDS: 2 dbuf x 2 half x [128][64]
// per operand = 128 KB. Per K-tile: 4 phases, each {asm ds_read, stage
// half-tile, barrier, lgkmcnt(0), setprio(1), 16 MFMA, setprio(0), barrier};
// one counted vmcnt(6) per K-tile (never 0 mid-loop). 16B XOR swizzle.
// 1-D grid with bijective XCD-chunk swizzle, y(M-block) fastest in-chunk.
#define NT 8                                      // K-tiles (K=512, BK=64)

__device__ __forceinline__ void stage_half(const bfr_t* g, short* l, int wid) {
  // g is lane-adjusted (soff folded in); wave stages 2 KB of the 16 KB half
  load_lds16(g + (size_t)wid * 8192,        l + wid * 1024);
  load_lds16(g + (size_t)wid * 8192 + 4096, l + wid * 1024 + 512);
}

#define CFENCE asm volatile("" ::: "memory")
#define PHASE_MID()                                          \
  do { CFENCE; __builtin_amdgcn_s_barrier();                 \
       asm volatile("s_waitcnt lgkmcnt(0)" ::: "memory");    \
       __builtin_amdgcn_sched_barrier(0); } while (0)
#define PHASE_END()                                          \
  do { CFENCE; __builtin_amdgcn_s_barrier(); CFENCE; } while (0)

// inline-asm ds_read_b128 with literal offset -- invisible to the compiler's
// LDS-DMA alias tracking (prevents inserted s_waitcnt vmcnt(0) drains).
#define DSR(dst, addr, lit) \
  asm volatile("ds_read_b128 %0, %1 offset:" lit : "=v"(dst) : "v"(addr))

#define LOAD_A0() do {                       \
    DSR(a_reg[0], aAs0, "0");                \
    DSR(a_reg[1], aAs1, "0");                \
    DSR(a_reg[2], aAs0, "2048");             \
    DSR(a_reg[3], aAs1, "2048");             \
    DSR(a_reg[4], aAs0, "4096");             \
    DSR(a_reg[5], aAs1, "4096");             \
    DSR(a_reg[6], aAs0, "6144");             \
    DSR(a_reg[7], aAs1, "6144"); } while (0)

#define LOAD_A1() do {                       \
    DSR(a_reg[0], aAs0, "8192");             \
    DSR(a_reg[1], aAs1, "8192");             \
    DSR(a_reg[2], aAs0, "10240");            \
    DSR(a_reg[3], aAs1, "10240");            \
    DSR(a_reg[4], aAs0, "12288");            \
    DSR(a_reg[5], aAs1, "12288");            \
    DSR(a_reg[6], aAs0, "14336");            \
    DSR(a_reg[7], aAs1, "14336"); } while (0)

#define LOAD_B0() do {                       \
    DSR(b_reg[0][0], bBs0, "0");             \
    DSR(b_reg[0][1], bBs1, "0");             \
    DSR(b_reg[0][2], bBs0, "2048");          \
    DSR(b_reg[0][3], bBs1, "2048"); } while (0)

#define LOAD_B1() do {                       \
    DSR(b_reg[1][0], bBs0, "4096");          \
    DSR(b_reg[1][1], bBs1, "4096");          \
    DSR(b_reg[1][2], bBs0, "6144");          \
    DSR(b_reg[1][3], bBs1, "6144"); } while (0)

#define MMA_Q(QM, QN) do {                                                   \
    __builtin_amdgcn_s_setprio(1);                                           \
    _Pragma("unroll") for (int i_ = 0; i_ < 4; ++i_) {                       \
      _Pragma("unroll") for (int j_ = 0; j_ < 2; ++j_) {                     \
        acc[(QM) * 4 + i_][(QN) * 2 + j_] =                                  \
            __builtin_amdgcn_mfma_f32_16x16x32_bf16(                         \
                a_reg[i_ * 2 + 0], b_reg[QN][j_ * 2 + 0],                    \
                acc[(QM) * 4 + i_][(QN) * 2 + j_], 0, 0, 0);                 \
        acc[(QM) * 4 + i_][(QN) * 2 + j_] =                                  \
            __builtin_amdgcn_mfma_f32_16x16x32_bf16(                         \
                a_reg[i_ * 2 + 1], b_reg[QN][j_ * 2 + 1],                    \
                acc[(QM) * 4 + i_][(QN) * 2 + j_], 0, 0, 0);                 \
      } }                                                                    \
    __builtin_amdgcn_s_setprio(0); } while (0)

__global__ __launch_bounds__(512, 2) void gemm256(
    const bfr_t* __restrict__ A, const bfr_t* __restrict__ Bt,
    bfr_t* __restrict__ Cout, const float* __restrict__ bias, int M) {
  __shared__ short lds[65536];          // 128 KB
  short* As = lds;                      // [2 buf][2 half][128][64]
  short* Bs = lds + 32768;

  // --- bijective XCD-chunk swizzle (nwg % 8 == 0), y fastest in-chunk ---
  // HW round-robins blocks over 8 XCDs (XCD = bid % 8); remap so each XCD
  // owns one contiguous logical chunk (= one batch) with the M-blocks that
  // share a B-panel temporally adjacent -> panel staged once into that L2.
  int nwg = gridDim.x;
  int gy = M >> 8;                      // M-blocks (6 for QKV, 2 for Wout)
  int bid = blockIdx.x;
  int logical = (bid & 7) * (nwg >> 3) + (bid >> 3);
  int perz = (LL / 256) * gy;
  int bz = logical / perz;
  int rem = logical - bz * perz;
  int bx = rem / gy;
  int by = rem - bx * gy;

  int m0 = by * 256, n0 = bx * 256;
  int t = threadIdx.x, lane = t & 63, wid = t >> 6;
  int quad = lane >> 4, r16 = lane & 15;
  int wm = wid >> 2, wn = wid & 3;
  // staging source offset: row (lane>>3), pre-swizzled granule (l&7)^(l>>3)
  int soff = (lane >> 3) * 512 + (((lane & 7) ^ (lane >> 3)) * 8);
  // ds_read swizzled k-granule slots (shorts): slot = gran ^ (row&7), x8
  int slot0 = (quad ^ (lane & 7)) * 8;          // ks=0
  int slot1 = ((4 + quad) ^ (lane & 7)) * 8;    // ks=1

  // LDS byte addresses for the asm ds_reads (per buf x per slot)
  unsigned lb = (unsigned)(uintptr_t)(__attribute__((address_space(3))) short*)lds;
  unsigned aA0_0 = lb + (unsigned)(wm * 16384 + r16 * 128 + slot0 * 2);
  unsigned aA0_1 = lb + (unsigned)(wm * 16384 + r16 * 128 + slot1 * 2);
  unsigned aA1_0 = aA0_0 + 32768u;
  unsigned aA1_1 = aA0_1 + 32768u;
  unsigned bbase = 65536u + (unsigned)((wn >> 1) * 16384 + ((wn & 1) * 64 + r16) * 128);
  unsigned bB0_0 = lb + bbase + (unsigned)(slot0 * 2);
  unsigned bB0_1 = lb + bbase + (unsigned)(slot1 * 2);
  unsigned bB1_0 = bB0_0 + 32768u;
  unsigned bB1_1 = bB0_1 + 32768u;

  const bfr_t* pA0 = A + (size_t)m0 * 512 + soff;
  const bfr_t* pA1 = pA0 + (size_t)128 * 512;
  const bfr_t* pB0 = Bt + (size_t)bz * LL * 512 + (size_t)n0 * 512 + soff;
  const bfr_t* pB1 = pB0 + (size_t)128 * 512;

  f32x4 acc[8][4] = {};
  short8 a_reg[8];
  short8 b_reg[2][4];

  // ---- prologue: stage K-tiles 0 and 1 (16 loads/wave) ----
  stage_half(pA0, As, wid);                    // t0 A0 -> buf0
  stage_half(pA1, As + 8192, wid);             // t0 A1
  stage_half(pB0, Bs, wid);                    // t0 B0
  stage_half(pB1, Bs + 8192, wid);             // t0 B1
  stage_half(pA0 + 64, As + 16384, wid);       // t1 A0 -> buf1
  stage_half(pA1 + 64, As + 24576, wid);       // t1 A1
  stage_half(pB0 + 64, Bs + 16384, wid);       // t1 B0
  stage_half(pB1 + 64, Bs + 24576, wid);       // t1 B1
  asm volatile("s_waitcnt vmcnt(8)" ::: "memory");   // tile 0 landed
  CFENCE; __builtin_amdgcn_s_barrier(); CFENCE;

#pragma unroll
  for (int kt = 0; kt < NT; ++kt) {
    const int buf = kt & 1;
    const unsigned aAs0 = buf ? aA1_0 : aA0_0;
    const unsigned aAs1 = buf ? aA1_1 : aA0_1;
    const unsigned bBs0 = buf ? bB1_0 : bB0_0;
    const unsigned bBs1 = buf ? bB1_1 : bB0_1;
    // ---- phase 1: quadrant (qm=0, qn=0); stage A1(kt+1) -> buf^1 ----
    LOAD_A0();
    LOAD_B0();
    if (kt >= 1 && kt <= NT - 2)
      stage_half(pA1 + (kt + 1) * 64, As + (((kt + 1) & 1) * 2 + 1) * 8192, wid);
    PHASE_MID();
    MMA_Q(0, 0);
    PHASE_END();
    // ---- phase 2: (0,1) ----
    LOAD_B1();
    PHASE_MID();
    MMA_Q(0, 1);
    PHASE_END();
    // ---- phase 3: (1,1); B halves of buf fully read -> stage B0(kt+2) ----
    LOAD_A1();
    if (kt <= NT - 3)
      stage_half(pB0 + (kt + 2) * 64, Bs + (buf * 2) * 8192, wid);
    PHASE_MID();
    MMA_Q(1, 1);
    PHASE_END();
    // ---- phase 4: (1,0); A halves fully read -> stage B1,A0(kt+2) ----
    if (kt <= NT - 3) {
      stage_half(pB1 + (kt + 2) * 64, Bs + (buf * 2 + 1) * 8192, wid);
      stage_half(pA0 + (kt + 2) * 64, As + (buf * 2) * 8192, wid);
    }
    PHASE_MID();
    MMA_Q(1, 0);
    __builtin_amdgcn_sched_barrier(0);
    // counted vmcnt: next tile's data landed, 3 half-tiles stay in flight
    if (kt <= NT - 3)      { asm volatile("s_waitcnt vmcnt(6)" ::: "memory"); }
    else if (kt == NT - 2) { asm volatile("s_waitcnt vmcnt(0)" ::: "memory"); }
    CFENCE; __builtin_amdgcn_s_barrier(); CFENCE;
  }

  // ---- epilogue: C write (+bias) ----
  bfr_t* Cb = Cout + (size_t)bz * M * LL;
  int crow = m0 + wm * 128 + quad * 4;
  int ccol = n0 + wn * 64 + r16;
#pragma unroll
  for (int am = 0; am < 8; ++am) {
    int rbase = crow + (am >> 2) * 64 + (am & 3) * 16;
#pragma unroll
    for (int reg = 0; reg < 4; ++reg) {
      int row = rbase + reg;
      float bi = bias ? bias[row] : 0.f;
#pragma unroll
      for (int an = 0; an < 4; ++an) {
        int col = ccol + (an >> 1) * 32 + (an & 1) * 16;
        Cb[(size_t)row * LL + col] = f2bf(acc[am][an][reg] + bi);
      }
    }
  }
}

// --------- context partials via MFMA: ctx_p[bh][s][d][e], n split 8 ---------
__global__ __launch_bounds__(256) void context_mfma(
    const bfr_t* __restrict__ qkv, float* __restrict__ ctx_p,
    float* __restrict__ ksum_p) {
  __shared__ float red[4][4096];      // 64 KB: per-wave 64x64 partial
  int s = blockIdx.x, bh = blockIdx.y;
  int b = bh >> 3, h = bh & 7;
  int t = threadIdx.x, lane = t & 63, wid = t >> 6;
  int quad = lane >> 4, r = lane & 15;
  const bfr_t* kb = qkv + ((size_t)b * TC + 512 + h * 64) * LL;   // raw k rows
  const bfr_t* vb = qkv + ((size_t)b * TC + 1024 + h * 64) * LL;  // v rows
  int n_base = s * 512 + wid * 128;
  f32x4 acc[4][4] = {};
  float ps[4] = {};                    // per-lane exp-sum partials, row d=i*16+r
#pragma unroll
  for (int ks = 0; ks < 4; ++ks) {
    int n0 = n_base + ks * 32;
    short8 af[4], bf8[4];
#pragma unroll
    for (int i = 0; i < 4; ++i) {
      union { short s[8]; short8 v8; } uk;
      uk.v8 = *(const short8*)&kb[(size_t)(i * 16 + r) * LL + n0 + quad * 8];
#pragma unroll
      for (int jj = 0; jj < 8; ++jj) {
        float e = __expf(bf2f((bfr_t)uk.s[jj]));
        uk.s[jj] = (short)f2bf(e);
        ps[i] += e;
      }
      af[i] = uk.v8;
      bf8[i] = *(const short8*)&vb[(size_t)(i * 16 + r) * LL + n0 + quad * 8];
    }
#pragma unroll
    for (int i = 0; i < 4; ++i)
#pragma unroll
      for (int j = 0; j < 4; ++j)
        acc[i][j] = __builtin_amdgcn_mfma_f32_16x16x32_bf16(af[i], bf8[j],
                                                            acc[i][j], 0, 0, 0);
  }
  // ksum: reduce across the quad lanes holding the same row d
#pragma unroll
  for (int i = 0; i < 4; ++i) {
    ps[i] += __shfl_xor(ps[i], 16, 64);
    ps[i] += __shfl_xor(ps[i], 32, 64);
  }
  if (quad == 0) {
#pragma unroll
    for (int i = 0; i < 4; ++i) red[wid][i * 16 + r] = ps[i];
  }
  __syncthreads();
  if (t < 64)
    ksum_p[((size_t)bh * 8 + s) * 64 + t] =
        red[0][t] + red[1][t] + red[2][t] + red[3][t];
  __syncthreads();
  // each wave writes its 64x64 partial to its LDS quadrant, then block-sum
#pragma unroll
  for (int i = 0; i < 4; ++i)
#pragma unroll
    for (int j = 0; j < 4; ++j)
#pragma unroll
      for (int reg = 0; reg < 4; ++reg)
        red[wid][(i * 16 + quad * 4 + reg) * 64 + j * 16 + r] = acc[i][j][reg];
  __syncthreads();
  float* out = ctx_p + ((size_t)bh * 8 + s) * 4096;
#pragma unroll
  for (int u = 0; u < 16; ++u) {
    int idx = u * 256 + t;
    out[idx] = red[0][idx] + red[1][idx] + red[2][idx] + red[3][idx];
  }
}

// ------- reduce partials, apply 1/Z -> ctx_bf[bh][d][e] (bf16) --------------
__global__ __launch_bounds__(256) void context_reduce(
    const float* __restrict__ ctx_p, const float* __restrict__ ksum_p,
    bfr_t* __restrict__ ctx_bf) {
  __shared__ float zinv[64];
  int bh = blockIdx.x;
  int t = threadIdx.x;
  if (t < 64) {
    float s = 0.f;
#pragma unroll
    for (int s8 = 0; s8 < 8; ++s8) s += ksum_p[((size_t)bh * 8 + s8) * 64 + t];
    zinv[t] = 1.f / s;
  }
  __syncthreads();
#pragma unroll
  for (int i = 0; i < 16; ++i) {
    int idx = i * 256 + t;            // idx = d*64 + e
    int d = idx >> 6;
    float sum = 0.f;
#pragma unroll
    for (int s = 0; s < 8; ++s) sum += ctx_p[((size_t)bh * 8 + s) * 4096 + idx];
    ctx_bf[(size_t)bh * 4096 + idx] = f2bf(sum * zinv[d]);
  }
}

// --- fused q-softmax + apply: out_t[b][n][h*64+e] = softmax_d(q)^T ctx -----
__global__ __launch_bounds__(256) void apply_fused(
    const bfr_t* __restrict__ qkv, const bfr_t* __restrict__ ctx_bf,
    bfr_t* __restrict__ out_t) {
  int b = blockIdx.z, h = blockIdx.y;
  int t = threadIdx.x, lane = t & 63, wid = t >> 6;
  int quad = lane >> 4, r = lane & 15;
  int n0 = blockIdx.x * 256 + wid * 64;
  const bfr_t* qb = qkv + ((size_t)b * TC + h * 64) * LL;   // q rows [d][n]
  const bfr_t* cb = ctx_bf + (size_t)(b * HH + h) * 4096;   // [d][e]
  float v[4][16];
  float pm[4];
#pragma unroll
  for (int i = 0; i < 4; ++i) {
    pm[i] = -1e30f;
#pragma unroll
    for (int ks = 0; ks < 2; ++ks)
#pragma unroll
      for (int jj = 0; jj < 8; ++jj) {
        float q = bf2f(qb[(size_t)(ks * 32 + quad * 8 + jj) * LL + n0 + i * 16 + r]);
        v[i][ks * 8 + jj] = q;
        pm[i] = fmaxf(pm[i], q);
      }
  }
#pragma unroll
  for (int i = 0; i < 4; ++i) {
    pm[i] = fmaxf(pm[i], __shfl_xor(pm[i], 16, 64));
    pm[i] = fmaxf(pm[i], __shfl_xor(pm[i], 32, 64));
  }
  float psum[4];
#pragma unroll
  for (int i = 0; i < 4; ++i) {
    float s = 0.f;
#pragma unroll
    for (int u = 0; u < 16; ++u) { v[i][u] = __expf(v[i][u] - pm[i]); s += v[i][u]; }
    psum[i] = s;
  }
#pragma unroll
  for (int i = 0; i < 4; ++i) {
    psum[i] += __shfl_xor(psum[i], 16, 64);
    psum[i] += __shfl_xor(psum[i], 32, 64);
  }
  short8 af[2][4];
#pragma unroll
  for (int i = 0; i < 4; ++i) {
    float sc = SCALE_Q / psum[i];
#pragma unroll
    for (int ks = 0; ks < 2; ++ks) {
      union { short s[8]; short8 v8; } u;
#pragma unroll
      for (int jj = 0; jj < 8; ++jj) u.s[jj] = (short)f2bf(v[i][ks * 8 + jj] * sc);
      af[ks][i] = u.v8;
    }
  }
  short8 bfrag[2][4];
#pragma unroll
  for (int ks = 0; ks < 2; ++ks)
#pragma unroll
    for (int j = 0; j < 4; ++j) {
      union { short s[8]; short8 v8; } u;
#pragma unroll
      for (int jj = 0; jj < 8; ++jj)
        u.s[jj] = (short)cb[(ks * 32 + quad * 8 + jj) * 64 + j * 16 + r];
      bfrag[ks][j] = u.v8;
    }
  f32x4 acc[4][4] = {};
#pragma unroll
  for (int ks = 0; ks < 2; ++ks)
#pragma unroll
    for (int i = 0; i < 4; ++i)
#pragma unroll
      for (int j = 0; j < 4; ++j)
        acc[i][j] = __builtin_amdgcn_mfma_f32_16x16x32_bf16(af[ks][i], bfrag[ks][j],
                                                            acc[i][j], 0, 0, 0);
  bfr_t* dst = out_t + (size_t)b * LL * 512 + h * 64;
#pragma unroll
  for (int i = 0; i < 4; ++i)
#pragma unroll
    for (int reg = 0; reg < 4; ++reg) {
      int row = n0 + i * 16 + quad * 4 + reg;
#pragma unroll
      for (int j = 0; j < 4; ++j)
        dst[(size_t)row * 512 + j * 16 + r] = f2bf(acc[i][j][reg]);
    }
}

// ------------------- final rmsnorm over c + residual add --------------------
__global__ __launch_bounds__(256) void final_norm_res(
    const bfr_t* __restrict__ o, const float* __restrict__ g,
    const float* __restrict__ x, float* __restrict__ out) {
  __shared__ float red[4][64];
  __shared__ float invn[64];
  int b = blockIdx.y, l0 = blockIdx.x * 64;
  int t = threadIdx.x, ll = t & 63, cg = t >> 6;
  const bfr_t* ob = o + (size_t)b * CC * LL + l0 + ll;
  float ss = 0.f;
  for (int c = cg * 128; c < cg * 128 + 128; ++c) {
    float v = bf2f(ob[(size_t)c * LL]);
    ss += v * v;
  }
  red[cg][ll] = ss;
  __syncthreads();
  if (cg == 0) {
    float s = red[0][ll] + red[1][ll] + red[2][ll] + red[3][ll];
    invn[ll] = SQRT_C / fmaxf(sqrtf(s), 1e-12f);
  }
  __syncthreads();
  float iv = invn[ll];
  const float* xb = x + (size_t)b * CC * LL + l0 + ll;
  float* outb = out + (size_t)b * CC * LL + l0 + ll;
  for (int c = cg * 128; c < cg * 128 + 128; ++c) {
    float v = bf2f(ob[(size_t)c * LL]);
    outb[(size_t)c * LL] = v * g[c] * iv + xb[(size_t)c * LL];
  }
}

// ---------------------------------------------------------------------------
extern "C" void kernel_launch(void* const* d_in, const int* in_sizes, int n_in,
                              void* d_out, int out_size, void* d_ws,
                              size_t ws_size, hipStream_t stream) {
  const float* x     = (const float*)d_in[0];
  const float* g_in  = (const float*)d_in[1];
  const float* w_qkv = (const float*)d_in[2];
  const float* w_out = (const float*)d_in[3];
  const float* b_out = (const float*)d_in[4];
  const float* g_out = (const float*)d_in[5];
  float* out = (float*)d_out;

  // workspace layout (bytes)
  char* ws = (char*)d_ws;
  const size_t off_wqkv  = 0;                       // 1536*512*2 = 1,572,864
  const size_t off_wout  = 1572864;                 // 512*512*2  =   524,288
  const size_t off_ksump = 2097152;                 // 64*8*64*4  =   131,072
  const size_t off_ctx   = 2260992;                 // 64*64*64*2 =   524,288 (bf16)
  const size_t off_ctxp  = 3309568;                 // 64*8*4096*4 = 8,388,608
  const size_t off_xt    = 11698176;                // 32MB  (xn_t, later out_t)
  const size_t off_qkv   = 45252608;                // 96MB  (later o_bf)
  const size_t ws_need   = 145915904;
  if (ws_size < ws_need) return;   // insufficient scratch -> fail loudly

  bfr_t* wqkv_bf = (bfr_t*)(ws + off_wqkv);
  bfr_t* wout_bf = (bfr_t*)(ws + off_wout);
  float* ksum_p  = (float*)(ws + off_ksump);
  bfr_t* ctx_bf  = (bfr_t*)(ws + off_ctx);
  float* ctxp    = (float*)(ws + off_ctxp);
  bfr_t* xt      = (bfr_t*)(ws + off_xt);    // xn_t then out_t (disjoint lifetimes)
  bfr_t* qkv     = (bfr_t*)(ws + off_qkv);
  bfr_t* o_bf    = (bfr_t*)(ws + off_qkv);   // overwrites dead q/k/v after apply

  // 1. weights -> bf16 (single vectorized launch)
  conv_bf16_2<<<dim3((1536 * 512 + 512 * 512) / 8 / 256), 256, 0, stream>>>(
      w_qkv, wqkv_bf, 1536 * 512, w_out, wout_bf, 512 * 512);
  // 2. fused input rmsnorm + transpose -> bf16 xt
  fused_norm_transpose<<<dim3(LL / 64, BB), 256, 0, stream>>>(x, g_in, xt);
  // 3. qkv = W_qkv @ xn   (256^2 8-phase GEMM, XCD-chunked 1-D grid)
  gemm256<<<dim3((LL / 256) * (TC / 256) * BB), 512, 0, stream>>>(wqkv_bf, xt, qkv, nullptr, TC);
  // 4. context = exp(k) v^T via MFMA (exp + ksum inline), reduce + 1/Z -> bf16
  context_mfma<<<dim3(8, BB * HH), 256, 0, stream>>>(qkv, ctxp, ksum_p);
  context_reduce<<<dim3(BB * HH), 256, 0, stream>>>(ctxp, ksum_p, ctx_bf);
  // 5. fused q-softmax + apply -> out_t (xn_t now dead)
  apply_fused<<<dim3(LL / 256, HH, BB), 256, 0, stream>>>(qkv, ctx_bf, xt);
  // 6. o = W_out @ out + b_out   (qkv fully dead now)
  gemm256<<<dim3((LL / 256) * (CC / 256) * BB), 512, 0, stream>>>(wout_bf, xt, o_bf, b_out, CC);
  // 7. final rmsnorm + residual -> fp32 out
  final_norm_res<<<dim3(LL / 64, BB), 256, 0, stream>>>(o_bf, g_out, x, out);
}

// Round 4
// 284.947 us; speedup vs baseline: 1.0839x; 1.0043x over previous
//
#include <hip/hip_runtime.h>

// ---------------------------------------------------------------------------
// LinearAttention (b=8, c=512, l=4096, heads=8, dim_head=64)
//   xn = rmsnorm_ch(x, g_in); qkv = W_qkv @ xn
//   q = softmax_d(q)*scale; k = softmax_l(k)
//   ctx = k v^T; out = ctx^T q; o = rmsnorm_ch(W_out @ out + b_out) + x
// GEMMs: 256x256 pipelined schedule, now 2 phases per K-tile (round-4 probe:
// barrier/rendezvous frequency). 8 waves, 128 KB LDS double-buffer, counted
// vmcnt(6) per K-tile, asm ds_read_b128, 16B XOR swizzle, XCD-chunked grid.
// final_norm_res: single-pass (o cached in registers, not re-read).
// ---------------------------------------------------------------------------

#define BB 8
#define CC 512
#define LL 4096
#define HH 8
#define DH 64
#define TC 1536

__device__ __constant__ const float SQRT_C = 22.62741699796952f;   // sqrt(512)
#define SCALE_Q 0.125f                                             // 64^-0.5

typedef unsigned short bfr_t;
typedef __attribute__((ext_vector_type(8))) short short8;
typedef __attribute__((ext_vector_type(4))) float f32x4;
typedef __attribute__((ext_vector_type(16))) float f32x16;

__device__ __forceinline__ float bf2f(bfr_t v) {
  union { unsigned u; float f; } c; c.u = ((unsigned)v) << 16; return c.f;
}
__device__ __forceinline__ bfr_t f2bf(float f) {
  union { float f; unsigned u; } c; c.f = f;
  unsigned u = c.u + 0x7fffu + ((c.u >> 16) & 1u);   // RNE, ignores NaN edge
  return (bfr_t)(u >> 16);
}

__device__ __forceinline__ void load_lds16(const bfr_t* g, short* l) {
  __builtin_amdgcn_global_load_lds(
      (const __attribute__((address_space(1))) void*)g,
      (__attribute__((address_space(3))) void*)l, 16, 0, 0);
}

// -------- f32 -> bf16 convert (both weights, vectorized x8, 1 launch) ------
__global__ __launch_bounds__(256) void conv_bf16_2(
    const float* __restrict__ in1, bfr_t* __restrict__ o1, int n1,
    const float* __restrict__ in2, bfr_t* __restrict__ o2, int n2) {
  int i8 = (blockIdx.x * 256 + threadIdx.x) * 8;
  const float* src;
  bfr_t* dst;
  if (i8 < n1) { src = in1 + i8; dst = o1 + i8; }
  else {
    int j8 = i8 - n1;
    if (j8 >= n2) return;
    src = in2 + j8; dst = o2 + j8;
  }
  f32x4 a = *(const f32x4*)src;
  f32x4 b = *(const f32x4*)(src + 4);
  union { short s[8]; f32x4 v; } pk;
#pragma unroll
  for (int u = 0; u < 4; ++u) { pk.s[u] = (short)f2bf(a[u]); pk.s[u + 4] = (short)f2bf(b[u]); }
  *(f32x4*)dst = pk.v;
}

// ------ fused channel-RMSNorm + transpose: x[b][c][l] -> xt[b][l][c] -------
__global__ __launch_bounds__(256) void fused_norm_transpose(
    const float* __restrict__ x, const float* __restrict__ g,
    bfr_t* __restrict__ xt) {
  __shared__ float tile[64][65];
  __shared__ float red[4][64];
  __shared__ float invn_s[64];
  int b = blockIdx.y, l0 = blockIdx.x * 64;
  int t = threadIdx.x, ll = t & 63, cg = t >> 6;
  const float* xb = x + (size_t)b * CC * LL + l0;
  float vals[8][16];
  float ss = 0.f;
#pragma unroll
  for (int ch = 0; ch < 8; ++ch) {
    int c0 = ch * 64;
#pragma unroll
    for (int i = 0; i < 16; ++i) {
      int c = i * 4 + cg;                       // chunk-local channel
      float v = xb[(size_t)(c0 + c) * LL + ll];
      vals[ch][i] = v;
      ss += v * v;
    }
  }
  red[cg][ll] = ss;
  __syncthreads();
  if (cg == 0) {
    float s = red[0][ll] + red[1][ll] + red[2][ll] + red[3][ll];
    invn_s[ll] = SQRT_C / fmaxf(sqrtf(s), 1e-12f);
  }
  __syncthreads();
  int lw = t >> 2, ccw = (t & 3) * 16;
  float iv = invn_s[lw];
#pragma unroll
  for (int ch = 0; ch < 8; ++ch) {
    int c0 = ch * 64;
#pragma unroll
    for (int i = 0; i < 16; ++i) tile[i * 4 + cg][ll] = vals[ch][i];
    __syncthreads();
    union { short s[16]; f32x4 v[2]; } pk;
#pragma unroll
    for (int u = 0; u < 16; ++u) {
      int c = ccw + u;
      pk.s[u] = (short)f2bf(tile[c][lw] * g[c0 + c] * iv);
    }
    bfr_t* dst = xt + ((size_t)b * LL + l0 + lw) * CC + c0 + ccw;
    *(f32x4*)dst = pk.v[0];
    *(f32x4*)(dst + 8) = pk.v[1];
    __syncthreads();
  }
}

// ----------------------- 256x256 2-phase bf16 GEMM -------------------------
// C[b][m][n] = sum_k A[m][k] * Bt[b][n][k] (+ bias[m]); A:[M][512], Bt:[B][L][512]
// 8 waves (2M x 4N), per-wave 128x64 out. LDS: 2 dbuf x 2 half x [128][64]
// per operand = 128 KB. Per K-tile: 2 phases {asm ds_read, stage, barrier,
// lgkmcnt(0), setprio(1), 32 MFMA, setprio(0), barrier}; one counted
// vmcnt(6) per K-tile (never 0 mid-loop). 16B XOR swizzle both sides.
// 1-D grid with bijective XCD-chunk swizzle, y(M-block) fastest in-chunk.
#define NT 8                                      // K-tiles (K=512, BK=64)

__device__ __forceinline__ void stage_half(const bfr_t* g, short* l, int wid) {
  // g is lane-adjusted (soff folded in); wave stages 2 KB of the 16 KB half
  load_lds16(g + (size_t)wid * 8192,        l + wid * 1024);
  load_lds16(g + (size_t)wid * 8192 + 4096, l + wid * 1024 + 512);
}

#define CFENCE asm volatile("" ::: "memory")
#define PHASE_MID()                                          \
  do { CFENCE; __builtin_amdgcn_s_barrier();                 \
       asm volatile("s_waitcnt lgkmcnt(0)" ::: "memory");    \
       __builtin_amdgcn_sched_barrier(0); } while (0)
#define PHASE_END()                                          \
  do { CFENCE; __builtin_amdgcn_s_barrier(); CFENCE; } while (0)

// inline-asm ds_read_b128 with literal offset -- invisible to the compiler's
// LDS-DMA alias tracking (prevents inserted s_waitcnt vmcnt(0) drains).
#define DSR(dst, addr, lit) \
  asm volatile("ds_read_b128 %0, %1 offset:" lit : "=v"(dst) : "v"(addr))

#define LOAD_A0() do {                       \
    DSR(a_reg[0], aAs0, "0");                \
    DSR(a_reg[1], aAs1, "0");                \
    DSR(a_reg[2], aAs0, "2048");             \
    DSR(a_reg[3], aAs1, "2048");             \
    DSR(a_reg[4], aAs0, "4096");             \
    DSR(a_reg[5], aAs1, "4096");             \
    DSR(a_reg[6], aAs0, "6144");             \
    DSR(a_reg[7], aAs1, "6144"); } while (0)

#define LOAD_A1() do {                       \
    DSR(a_reg[0], aAs0, "8192");             \
    DSR(a_reg[1], aAs1, "8192");             \
    DSR(a_reg[2], aAs0, "10240");            \
    DSR(a_reg[3], aAs1, "10240");            \
    DSR(a_reg[4], aAs0, "12288");            \
    DSR(a_reg[5], aAs1, "12288");            \
    DSR(a_reg[6], aAs0, "14336");            \
    DSR(a_reg[7], aAs1, "14336"); } while (0)

#define LOAD_B0() do {                       \
    DSR(b_reg[0][0], bBs0, "0");             \
    DSR(b_reg[0][1], bBs1, "0");             \
    DSR(b_reg[0][2], bBs0, "2048");          \
    DSR(b_reg[0][3], bBs1, "2048"); } while (0)

#define LOAD_B1() do {                       \
    DSR(b_reg[1][0], bBs0, "4096");          \
    DSR(b_reg[1][1], bBs1, "4096");          \
    DSR(b_reg[1][2], bBs0, "6144");          \
    DSR(b_reg[1][3], bBs1, "6144"); } while (0)

#define MMA_Q(QM, QN) do {                                                   \
    _Pragma("unroll") for (int i_ = 0; i_ < 4; ++i_) {                       \
      _Pragma("unroll") for (int j_ = 0; j_ < 2; ++j_) {                     \
        acc[(QM) * 4 + i_][(QN) * 2 + j_] =                                  \
            __builtin_amdgcn_mfma_f32_16x16x32_bf16(                         \
                a_reg[i_ * 2 + 0], b_reg[QN][j_ * 2 + 0],                    \
                acc[(QM) * 4 + i_][(QN) * 2 + j_], 0, 0, 0);                 \
        acc[(QM) * 4 + i_][(QN) * 2 + j_] =                                  \
            __builtin_amdgcn_mfma_f32_16x16x32_bf16(                         \
                a_reg[i_ * 2 + 1], b_reg[QN][j_ * 2 + 1],                    \
                acc[(QM) * 4 + i_][(QN) * 2 + j_], 0, 0, 0);                 \
      } } } while (0)

__global__ __launch_bounds__(512, 2) void gemm256(
    const bfr_t* __restrict__ A, const bfr_t* __restrict__ Bt,
    bfr_t* __restrict__ Cout, const float* __restrict__ bias, int M) {
  __shared__ short lds[65536];          // 128 KB
  short* As = lds;                      // [2 buf][2 half][128][64]
  short* Bs = lds + 32768;

  // --- bijective XCD-chunk swizzle (nwg % 8 == 0), y fastest in-chunk ---
  int nwg = gridDim.x;
  int gy = M >> 8;                      // M-blocks (6 for QKV, 2 for Wout)
  int bid = blockIdx.x;
  int logical = (bid & 7) * (nwg >> 3) + (bid >> 3);
  int perz = (LL / 256) * gy;
  int bz = logical / perz;
  int rem = logical - bz * perz;
  int bx = rem / gy;
  int by = rem - bx * gy;

  int m0 = by * 256, n0 = bx * 256;
  int t = threadIdx.x, lane = t & 63, wid = t >> 6;
  int quad = lane >> 4, r16 = lane & 15;
  int wm = wid >> 2, wn = wid & 3;
  // staging source offset: row (lane>>3), pre-swizzled granule (l&7)^(l>>3)
  int soff = (lane >> 3) * 512 + (((lane & 7) ^ (lane >> 3)) * 8);
  // ds_read swizzled k-granule slots (shorts): slot = gran ^ (row&7), x8
  int slot0 = (quad ^ (lane & 7)) * 8;          // ks=0
  int slot1 = ((4 + quad) ^ (lane & 7)) * 8;    // ks=1

  // LDS byte addresses for the asm ds_reads (per buf x per slot)
  unsigned lb = (unsigned)(uintptr_t)(__attribute__((address_space(3))) short*)lds;
  unsigned aA0_0 = lb + (unsigned)(wm * 16384 + r16 * 128 + slot0 * 2);
  unsigned aA0_1 = lb + (unsigned)(wm * 16384 + r16 * 128 + slot1 * 2);
  unsigned aA1_0 = aA0_0 + 32768u;
  unsigned aA1_1 = aA0_1 + 32768u;
  unsigned bbase = 65536u + (unsigned)((wn >> 1) * 16384 + ((wn & 1) * 64 + r16) * 128);
  unsigned bB0_0 = lb + bbase + (unsigned)(slot0 * 2);
  unsigned bB0_1 = lb + bbase + (unsigned)(slot1 * 2);
  unsigned bB1_0 = bB0_0 + 32768u;
  unsigned bB1_1 = bB0_1 + 32768u;

  const bfr_t* pA0 = A + (size_t)m0 * 512 + soff;
  const bfr_t* pA1 = pA0 + (size_t)128 * 512;
  const bfr_t* pB0 = Bt + (size_t)bz * LL * 512 + (size_t)n0 * 512 + soff;
  const bfr_t* pB1 = pB0 + (size_t)128 * 512;

  f32x4 acc[8][4] = {};
  short8 a_reg[8];
  short8 b_reg[2][4];

  // ---- prologue: stage K-tiles 0 and 1 (16 loads/wave) ----
  stage_half(pA0, As, wid);                    // t0 A0 -> buf0
  stage_half(pA1, As + 8192, wid);             // t0 A1
  stage_half(pB0, Bs, wid);                    // t0 B0
  stage_half(pB1, Bs + 8192, wid);             // t0 B1
  stage_half(pA0 + 64, As + 16384, wid);       // t1 A0 -> buf1
  stage_half(pA1 + 64, As + 24576, wid);       // t1 A1
  stage_half(pB0 + 64, Bs + 16384, wid);       // t1 B0
  stage_half(pB1 + 64, Bs + 24576, wid);       // t1 B1
  asm volatile("s_waitcnt vmcnt(8)" ::: "memory");   // tile 0 landed
  CFENCE; __builtin_amdgcn_s_barrier(); CFENCE;

#pragma unroll
  for (int kt = 0; kt < NT; ++kt) {
    const int buf = kt & 1;
    const unsigned aAs0 = buf ? aA1_0 : aA0_0;
    const unsigned aAs1 = buf ? aA1_1 : aA0_1;
    const unsigned bBs0 = buf ? bB1_0 : bB0_0;
    const unsigned bBs1 = buf ? bB1_1 : bB0_1;
    // ---- phase A: quadrants (0,0),(0,1); stage A1(kt+1) -> buf^1 ----
    LOAD_A0();
    LOAD_B0();
    LOAD_B1();
    if (kt >= 1 && kt <= NT - 2)
      stage_half(pA1 + (kt + 1) * 64, As + (((kt + 1) & 1) * 2 + 1) * 8192, wid);
    PHASE_MID();
    __builtin_amdgcn_s_setprio(1);
    MMA_Q(0, 0);
    MMA_Q(0, 1);
    __builtin_amdgcn_s_setprio(0);
    PHASE_END();
    // ---- phase B: quadrants (1,1),(1,0); stage B0,B1,A0(kt+2) ----
    LOAD_A1();
    if (kt <= NT - 3) {
      stage_half(pB0 + (kt + 2) * 64, Bs + (buf * 2) * 8192, wid);
      stage_half(pB1 + (kt + 2) * 64, Bs + (buf * 2 + 1) * 8192, wid);
      stage_half(pA0 + (kt + 2) * 64, As + (buf * 2) * 8192, wid);
    }
    PHASE_MID();
    __builtin_amdgcn_s_setprio(1);
    MMA_Q(1, 1);
    MMA_Q(1, 0);
    __builtin_amdgcn_s_setprio(0);
    __builtin_amdgcn_sched_barrier(0);
    // counted vmcnt: next tile's data landed, 3 half-tiles stay in flight
    if (kt <= NT - 3)      { asm volatile("s_waitcnt vmcnt(6)" ::: "memory"); }
    else if (kt == NT - 2) { asm volatile("s_waitcnt vmcnt(0)" ::: "memory"); }
    CFENCE; __builtin_amdgcn_s_barrier(); CFENCE;
  }

  // ---- epilogue: C write (+bias) ----
  bfr_t* Cb = Cout + (size_t)bz * M * LL;
  int crow = m0 + wm * 128 + quad * 4;
  int ccol = n0 + wn * 64 + r16;
#pragma unroll
  for (int am = 0; am < 8; ++am) {
    int rbase = crow + (am >> 2) * 64 + (am & 3) * 16;
#pragma unroll
    for (int reg = 0; reg < 4; ++reg) {
      int row = rbase + reg;
      float bi = bias ? bias[row] : 0.f;
#pragma unroll
      for (int an = 0; an < 4; ++an) {
        int col = ccol + (an >> 1) * 32 + (an & 1) * 16;
        Cb[(size_t)row * LL + col] = f2bf(acc[am][an][reg] + bi);
      }
    }
  }
}

// --------- context partials via MFMA: ctx_p[bh][s][d][e], n split 8 ---------
__global__ __launch_bounds__(256) void context_mfma(
    const bfr_t* __restrict__ qkv, float* __restrict__ ctx_p,
    float* __restrict__ ksum_p) {
  __shared__ float red[4][4096];      // 64 KB: per-wave 64x64 partial
  int s = blockIdx.x, bh = blockIdx.y;
  int b = bh >> 3, h = bh & 7;
  int t = threadIdx.x, lane = t & 63, wid = t >> 6;
  int quad = lane >> 4, r = lane & 15;
  const bfr_t* kb = qkv + ((size_t)b * TC + 512 + h * 64) * LL;   // raw k rows
  const bfr_t* vb = qkv + ((size_t)b * TC + 1024 + h * 64) * LL;  // v rows
  int n_base = s * 512 + wid * 128;
  f32x4 acc[4][4] = {};
  float ps[4] = {};                    // per-lane exp-sum partials, row d=i*16+r
#pragma unroll
  for (int ks = 0; ks < 4; ++ks) {
    int n0 = n_base + ks * 32;
    short8 af[4], bf8[4];
#pragma unroll
    for (int i = 0; i < 4; ++i) {
      union { short s[8]; short8 v8; } uk;
      uk.v8 = *(const short8*)&kb[(size_t)(i * 16 + r) * LL + n0 + quad * 8];
#pragma unroll
      for (int jj = 0; jj < 8; ++jj) {
        float e = __expf(bf2f((bfr_t)uk.s[jj]));
        uk.s[jj] = (short)f2bf(e);
        ps[i] += e;
      }
      af[i] = uk.v8;
      bf8[i] = *(const short8*)&vb[(size_t)(i * 16 + r) * LL + n0 + quad * 8];
    }
#pragma unroll
    for (int i = 0; i < 4; ++i)
#pragma unroll
      for (int j = 0; j < 4; ++j)
        acc[i][j] = __builtin_amdgcn_mfma_f32_16x16x32_bf16(af[i], bf8[j],
                                                            acc[i][j], 0, 0, 0);
  }
  // ksum: reduce across the quad lanes holding the same row d
#pragma unroll
  for (int i = 0; i < 4; ++i) {
    ps[i] += __shfl_xor(ps[i], 16, 64);
    ps[i] += __shfl_xor(ps[i], 32, 64);
  }
  if (quad == 0) {
#pragma unroll
    for (int i = 0; i < 4; ++i) red[wid][i * 16 + r] = ps[i];
  }
  __syncthreads();
  if (t < 64)
    ksum_p[((size_t)bh * 8 + s) * 64 + t] =
        red[0][t] + red[1][t] + red[2][t] + red[3][t];
  __syncthreads();
  // each wave writes its 64x64 partial to its LDS quadrant, then block-sum
#pragma unroll
  for (int i = 0; i < 4; ++i)
#pragma unroll
    for (int j = 0; j < 4; ++j)
#pragma unroll
      for (int reg = 0; reg < 4; ++reg)
        red[wid][(i * 16 + quad * 4 + reg) * 64 + j * 16 + r] = acc[i][j][reg];
  __syncthreads();
  float* out = ctx_p + ((size_t)bh * 8 + s) * 4096;
#pragma unroll
  for (int u = 0; u < 16; ++u) {
    int idx = u * 256 + t;
    out[idx] = red[0][idx] + red[1][idx] + red[2][idx] + red[3][idx];
  }
}

// ------- reduce partials, apply 1/Z -> ctx_bf[bh][d][e] (bf16) --------------
__global__ __launch_bounds__(256) void context_reduce(
    const float* __restrict__ ctx_p, const float* __restrict__ ksum_p,
    bfr_t* __restrict__ ctx_bf) {
  __shared__ float zinv[64];
  int bh = blockIdx.x;
  int t = threadIdx.x;
  if (t < 64) {
    float s = 0.f;
#pragma unroll
    for (int s8 = 0; s8 < 8; ++s8) s += ksum_p[((size_t)bh * 8 + s8) * 64 + t];
    zinv[t] = 1.f / s;
  }
  __syncthreads();
#pragma unroll
  for (int i = 0; i < 16; ++i) {
    int idx = i * 256 + t;            // idx = d*64 + e
    int d = idx >> 6;
    float sum = 0.f;
#pragma unroll
    for (int s = 0; s < 8; ++s) sum += ctx_p[((size_t)bh * 8 + s) * 4096 + idx];
    ctx_bf[(size_t)bh * 4096 + idx] = f2bf(sum * zinv[d]);
  }
}

// --- fused q-softmax + apply: out_t[b][n][h*64+e] = softmax_d(q)^T ctx -----
__global__ __launch_bounds__(256) void apply_fused(
    const bfr_t* __restrict__ qkv, const bfr_t* __restrict__ ctx_bf,
    bfr_t* __restrict__ out_t) {
  int b = blockIdx.z, h = blockIdx.y;
  int t = threadIdx.x, lane = t & 63, wid = t >> 6;
  int quad = lane >> 4, r = lane & 15;
  int n0 = blockIdx.x * 256 + wid * 64;
  const bfr_t* qb = qkv + ((size_t)b * TC + h * 64) * LL;   // q rows [d][n]
  const bfr_t* cb = ctx_bf + (size_t)(b * HH + h) * 4096;   // [d][e]
  float v[4][16];
  float pm[4];
#pragma unroll
  for (int i = 0; i < 4; ++i) {
    pm[i] = -1e30f;
#pragma unroll
    for (int ks = 0; ks < 2; ++ks)
#pragma unroll
      for (int jj = 0; jj < 8; ++jj) {
        float q = bf2f(qb[(size_t)(ks * 32 + quad * 8 + jj) * LL + n0 + i * 16 + r]);
        v[i][ks * 8 + jj] = q;
        pm[i] = fmaxf(pm[i], q);
      }
  }
#pragma unroll
  for (int i = 0; i < 4; ++i) {
    pm[i] = fmaxf(pm[i], __shfl_xor(pm[i], 16, 64));
    pm[i] = fmaxf(pm[i], __shfl_xor(pm[i], 32, 64));
  }
  float psum[4];
#pragma unroll
  for (int i = 0; i < 4; ++i) {
    float s = 0.f;
#pragma unroll
    for (int u = 0; u < 16; ++u) { v[i][u] = __expf(v[i][u] - pm[i]); s += v[i][u]; }
    psum[i] = s;
  }
#pragma unroll
  for (int i = 0; i < 4; ++i) {
    psum[i] += __shfl_xor(psum[i], 16, 64);
    psum[i] += __shfl_xor(psum[i], 32, 64);
  }
  short8 af[2][4];
#pragma unroll
  for (int i = 0; i < 4; ++i) {
    float sc = SCALE_Q / psum[i];
#pragma unroll
    for (int ks = 0; ks < 2; ++ks) {
      union { short s[8]; short8 v8; } u;
#pragma unroll
      for (int jj = 0; jj < 8; ++jj) u.s[jj] = (short)f2bf(v[i][ks * 8 + jj] * sc);
      af[ks][i] = u.v8;
    }
  }
  short8 bfrag[2][4];
#pragma unroll
  for (int ks = 0; ks < 2; ++ks)
#pragma unroll
    for (int j = 0; j < 4; ++j) {
      union { short s[8]; short8 v8; } u;
#pragma unroll
      for (int jj = 0; jj < 8; ++jj)
        u.s[jj] = (short)cb[(ks * 32 + quad * 8 + jj) * 64 + j * 16 + r];
      bfrag[ks][j] = u.v8;
    }
  f32x4 acc[4][4] = {};
#pragma unroll
  for (int ks = 0; ks < 2; ++ks)
#pragma unroll
    for (int i = 0; i < 4; ++i)
#pragma unroll
      for (int j = 0; j < 4; ++j)
        acc[i][j] = __builtin_amdgcn_mfma_f32_16x16x32_bf16(af[ks][i], bfrag[ks][j],
                                                            acc[i][j], 0, 0, 0);
  bfr_t* dst = out_t + (size_t)b * LL * 512 + h * 64;
#pragma unroll
  for (int i = 0; i < 4; ++i)
#pragma unroll
    for (int reg = 0; reg < 4; ++reg) {
      int row = n0 + i * 16 + quad * 4 + reg;
#pragma unroll
      for (int j = 0; j < 4; ++j)
        dst[(size_t)row * 512 + j * 16 + r] = f2bf(acc[i][j][reg]);
    }
}

// ------------- final rmsnorm over c + residual add (single-pass) -----------
// o cached in 64 packed dwords per thread (128 channels); no o re-read.
__global__ __launch_bounds__(256) void final_norm_res(
    const bfr_t* __restrict__ o, const float* __restrict__ g,
    const float* __restrict__ x, float* __restrict__ out) {
  __shared__ float red[4][64];
  __shared__ float invn[64];
  int b = blockIdx.y, l0 = blockIdx.x * 64;
  int t = threadIdx.x, ll = t & 63, cg = t >> 6;
  const bfr_t* ob = o + (size_t)b * CC * LL + l0 + ll;
  unsigned pk[64];
  float ss = 0.f;
#pragma unroll
  for (int i = 0; i < 64; ++i) {
    int c = cg * 128 + 2 * i;
    unsigned u0 = ob[(size_t)c * LL];
    unsigned u1 = ob[(size_t)(c + 1) * LL];
    float v0 = bf2f((bfr_t)u0), v1 = bf2f((bfr_t)u1);
    ss += v0 * v0 + v1 * v1;
    pk[i] = u0 | (u1 << 16);
  }
  red[cg][ll] = ss;
  __syncthreads();
  if (cg == 0) {
    float s = red[0][ll] + red[1][ll] + red[2][ll] + red[3][ll];
    invn[ll] = SQRT_C / fmaxf(sqrtf(s), 1e-12f);
  }
  __syncthreads();
  float iv = invn[ll];
  const float* xb = x + (size_t)b * CC * LL + l0 + ll;
  float* outb = out + (size_t)b * CC * LL + l0 + ll;
#pragma unroll
  for (int i = 0; i < 64; ++i) {
    int c = cg * 128 + 2 * i;
    float v0 = bf2f((bfr_t)(pk[i] & 0xffffu));
    float v1 = bf2f((bfr_t)(pk[i] >> 16));
    outb[(size_t)c * LL] = v0 * g[c] * iv + xb[(size_t)c * LL];
    outb[(size_t)(c + 1) * LL] = v1 * g[c + 1] * iv + xb[(size_t)(c + 1) * LL];
  }
}

// ---------------------------------------------------------------------------
extern "C" void kernel_launch(void* const* d_in, const int* in_sizes, int n_in,
                              void* d_out, int out_size, void* d_ws,
                              size_t ws_size, hipStream_t stream) {
  const float* x     = (const float*)d_in[0];
  const float* g_in  = (const float*)d_in[1];
  const float* w_qkv = (const float*)d_in[2];
  const float* w_out = (const float*)d_in[3];
  const float* b_out = (const float*)d_in[4];
  const float* g_out = (const float*)d_in[5];
  float* out = (float*)d_out;

  // workspace layout (bytes)
  char* ws = (char*)d_ws;
  const size_t off_wqkv  = 0;                       // 1536*512*2 = 1,572,864
  const size_t off_wout  = 1572864;                 // 512*512*2  =   524,288
  const size_t off_ksump = 2097152;                 // 64*8*64*4  =   131,072
  const size_t off_ctx   = 2260992;                 // 64*64*64*2 =   524,288 (bf16)
  const size_t off_ctxp  = 3309568;                 // 64*8*4096*4 = 8,388,608
  const size_t off_xt    = 11698176;                // 32MB  (xn_t, later out_t)
  const size_t off_qkv   = 45252608;                // 96MB  (later o_bf)
  const size_t ws_need   = 145915904;
  if (ws_size < ws_need) return;   // insufficient scratch -> fail loudly

  bfr_t* wqkv_bf = (bfr_t*)(ws + off_wqkv);
  bfr_t* wout_bf = (bfr_t*)(ws + off_wout);
  float* ksum_p  = (float*)(ws + off_ksump);
  bfr_t* ctx_bf  = (bfr_t*)(ws + off_ctx);
  float* ctxp    = (float*)(ws + off_ctxp);
  bfr_t* xt      = (bfr_t*)(ws + off_xt);    // xn_t then out_t (disjoint lifetimes)
  bfr_t* qkv     = (bfr_t*)(ws + off_qkv);
  bfr_t* o_bf    = (bfr_t*)(ws + off_qkv);   // overwrites dead q/k/v after apply

  // 1. weights -> bf16 (single vectorized launch)
  conv_bf16_2<<<dim3((1536 * 512 + 512 * 512) / 8 / 256), 256, 0, stream>>>(
      w_qkv, wqkv_bf, 1536 * 512, w_out, wout_bf, 512 * 512);
  // 2. fused input rmsnorm + transpose -> bf16 xt
  fused_norm_transpose<<<dim3(LL / 64, BB), 256, 0, stream>>>(x, g_in, xt);
  // 3. qkv = W_qkv @ xn   (256^2 2-phase GEMM, XCD-chunked 1-D grid)
  gemm256<<<dim3((LL / 256) * (TC / 256) * BB), 512, 0, stream>>>(wqkv_bf, xt, qkv, nullptr, TC);
  // 4. context = exp(k) v^T via MFMA (exp + ksum inline), reduce + 1/Z -> bf16
  context_mfma<<<dim3(8, BB * HH), 256, 0, stream>>>(qkv, ctxp, ksum_p);
  context_reduce<<<dim3(BB * HH), 256, 0, stream>>>(ctxp, ksum_p, ctx_bf);
  // 5. fused q-softmax + apply -> out_t (xn_t now dead)
  apply_fused<<<dim3(LL / 256, HH, BB), 256, 0, stream>>>(qkv, ctx_bf, xt);
  // 6. o = W_out @ out + b_out   (qkv fully dead now)
  gemm256<<<dim3((LL / 256) * (CC / 256) * BB), 512, 0, stream>>>(wout_bf, xt, o_bf, b_out, CC);
  // 7. final rmsnorm + residual -> fp32 out
  final_norm_res<<<dim3(LL / 64, BB), 256, 0, stream>>>(o_bf, g_out, x, out);
}

// Round 5
// 280.882 us; speedup vs baseline: 1.0996x; 1.0145x over previous
//
#include <hip/hip_runtime.h>

// ---------------------------------------------------------------------------
// LinearAttention (b=8, c=512, l=4096, heads=8, dim_head=64)
//   xn = rmsnorm_ch(x, g_in); qkv = W_qkv @ xn
//   q = softmax_d(q)*scale; k = softmax_l(k)
//   ctx = k v^T; out = ctx^T q; o = rmsnorm_ch(W_out @ out + b_out) + x
// GEMM v5: 256x256, 8 waves, REGISTER-PIPELINED sub-phases -- ds_reads for
// sub-phase s+1 issue during sub-phase s's MFMA cluster (LDS pipe overlaps
// matrix pipe; rounds 1-4 were serial: reads -> lgkm0 -> MFMA -> barrier).
// One vmcnt(0)+s_barrier per K-tile. Double fragment sets (+32 VGPR).
// ---------------------------------------------------------------------------

#define BB 8
#define CC 512
#define LL 4096
#define HH 8
#define DH 64
#define TC 1536

__device__ __constant__ const float SQRT_C = 22.62741699796952f;   // sqrt(512)
#define SCALE_Q 0.125f                                             // 64^-0.5

typedef unsigned short bfr_t;
typedef __attribute__((ext_vector_type(8))) short short8;
typedef __attribute__((ext_vector_type(4))) float f32x4;

__device__ __forceinline__ float bf2f(bfr_t v) {
  union { unsigned u; float f; } c; c.u = ((unsigned)v) << 16; return c.f;
}
__device__ __forceinline__ bfr_t f2bf(float f) {
  union { float f; unsigned u; } c; c.f = f;
  unsigned u = c.u + 0x7fffu + ((c.u >> 16) & 1u);   // RNE, ignores NaN edge
  return (bfr_t)(u >> 16);
}

__device__ __forceinline__ void load_lds16(const bfr_t* g, short* l) {
  __builtin_amdgcn_global_load_lds(
      (const __attribute__((address_space(1))) void*)g,
      (__attribute__((address_space(3))) void*)l, 16, 0, 0);
}

// -------- f32 -> bf16 convert (both weights, vectorized x8, 1 launch) ------
__global__ __launch_bounds__(256) void conv_bf16_2(
    const float* __restrict__ in1, bfr_t* __restrict__ o1, int n1,
    const float* __restrict__ in2, bfr_t* __restrict__ o2, int n2) {
  int i8 = (blockIdx.x * 256 + threadIdx.x) * 8;
  const float* src;
  bfr_t* dst;
  if (i8 < n1) { src = in1 + i8; dst = o1 + i8; }
  else {
    int j8 = i8 - n1;
    if (j8 >= n2) return;
    src = in2 + j8; dst = o2 + j8;
  }
  f32x4 a = *(const f32x4*)src;
  f32x4 b = *(const f32x4*)(src + 4);
  union { short s[8]; f32x4 v; } pk;
#pragma unroll
  for (int u = 0; u < 4; ++u) { pk.s[u] = (short)f2bf(a[u]); pk.s[u + 4] = (short)f2bf(b[u]); }
  *(f32x4*)dst = pk.v;
}

// ------ fused channel-RMSNorm + transpose: x[b][c][l] -> xt[b][l][c] -------
__global__ __launch_bounds__(256) void fused_norm_transpose(
    const float* __restrict__ x, const float* __restrict__ g,
    bfr_t* __restrict__ xt) {
  __shared__ float tile[64][65];
  __shared__ float red[4][64];
  __shared__ float invn_s[64];
  int b = blockIdx.y, l0 = blockIdx.x * 64;
  int t = threadIdx.x, ll = t & 63, cg = t >> 6;
  const float* xb = x + (size_t)b * CC * LL + l0;
  float vals[8][16];
  float ss = 0.f;
#pragma unroll
  for (int ch = 0; ch < 8; ++ch) {
    int c0 = ch * 64;
#pragma unroll
    for (int i = 0; i < 16; ++i) {
      int c = i * 4 + cg;                       // chunk-local channel
      float v = xb[(size_t)(c0 + c) * LL + ll];
      vals[ch][i] = v;
      ss += v * v;
    }
  }
  red[cg][ll] = ss;
  __syncthreads();
  if (cg == 0) {
    float s = red[0][ll] + red[1][ll] + red[2][ll] + red[3][ll];
    invn_s[ll] = SQRT_C / fmaxf(sqrtf(s), 1e-12f);
  }
  __syncthreads();
  int lw = t >> 2, ccw = (t & 3) * 16;
  float iv = invn_s[lw];
#pragma unroll
  for (int ch = 0; ch < 8; ++ch) {
    int c0 = ch * 64;
#pragma unroll
    for (int i = 0; i < 16; ++i) tile[i * 4 + cg][ll] = vals[ch][i];
    __syncthreads();
    union { short s[16]; f32x4 v[2]; } pk;
#pragma unroll
    for (int u = 0; u < 16; ++u) {
      int c = ccw + u;
      pk.s[u] = (short)f2bf(tile[c][lw] * g[c0 + c] * iv);
    }
    bfr_t* dst = xt + ((size_t)b * LL + l0 + lw) * CC + c0 + ccw;
    *(f32x4*)dst = pk.v[0];
    *(f32x4*)(dst + 8) = pk.v[1];
    __syncthreads();
  }
}

// ------------- 256x256 register-pipelined sub-phase bf16 GEMM --------------
// C[b][m][n] = sum_k A[m][k] * Bt[b][n][k] (+ bias[m]); A:[M][512], Bt:[B][L][512]
// 8 waves (2M x 4N), per-wave 128x64. LDS [2buf][2half][128][64] per op=128KB.
// Per K-tile: 4 sub-phases of 8 MFMA (quadrants q00,q01,q11,q10); sub-phase s
// consumes frags read in s-1, issues reads for s+1 (sets aS0/aS1/bS0/bS1).
// One vmcnt(0)+barrier per tile (cooperative DMA confirm + buf WAR free).
// Staging kt+2 issues at kt's sub2 (2-tile latency cover). 16B XOR swizzle.
#define NT 8                                      // K-tiles (K=512, BK=64)

__device__ __forceinline__ void stage_half(const bfr_t* g, short* l, int wid) {
  load_lds16(g + (size_t)wid * 8192,        l + wid * 1024);
  load_lds16(g + (size_t)wid * 8192 + 4096, l + wid * 1024 + 512);
}

#define CFENCE asm volatile("" ::: "memory")
#define LGKM0 asm volatile("s_waitcnt lgkmcnt(0)" ::: "memory")
#define VMC0  asm volatile("s_waitcnt vmcnt(0)" ::: "memory")
#define SB    __builtin_amdgcn_sched_barrier(0)
#define BAR   do { CFENCE; __builtin_amdgcn_s_barrier(); CFENCE; } while (0)
#define PRIO1 __builtin_amdgcn_s_setprio(1)
#define PRIO0 __builtin_amdgcn_s_setprio(0)

#define DSR(dst, addr, LIT) \
  asm volatile("ds_read_b128 %0, %1 offset:" #LIT : "=v"(dst) : "v"(addr))

// A-half read: 8 frags (4 row-groups x 2 k-slots); literals = buf*32768+h*8192+i*2048
#define RD_A(S, L0, L1, L2, L3) do {           \
    DSR(S[0], aAs0, L0); DSR(S[1], aAs1, L0);  \
    DSR(S[2], aAs0, L1); DSR(S[3], aAs1, L1);  \
    DSR(S[4], aAs0, L2); DSR(S[5], aAs1, L2);  \
    DSR(S[6], aAs0, L3); DSR(S[7], aAs1, L3); } while (0)
// B col-half read: 4 frags (2 col-16-groups x 2 k-slots); lit = buf*32768+c*4096+j*2048
#define RD_B(S, L0, L1) do {                   \
    DSR(S[0], bBs0, L0); DSR(S[1], bBs1, L0);  \
    DSR(S[2], bBs0, L1); DSR(S[3], bBs1, L1); } while (0)

#define MMA8(QM, QN, AS, BS) do {                                            \
    _Pragma("unroll") for (int i_ = 0; i_ < 4; ++i_)                         \
      _Pragma("unroll") for (int j_ = 0; j_ < 2; ++j_) {                     \
        acc[(QM)*4+i_][(QN)*2+j_] = __builtin_amdgcn_mfma_f32_16x16x32_bf16( \
            AS[i_*2+0], BS[j_*2+0], acc[(QM)*4+i_][(QN)*2+j_], 0, 0, 0);     \
        acc[(QM)*4+i_][(QN)*2+j_] = __builtin_amdgcn_mfma_f32_16x16x32_bf16( \
            AS[i_*2+1], BS[j_*2+1], acc[(QM)*4+i_][(QN)*2+j_], 0, 0, 0);     \
      }                                                                      \
  } while (0)

#define STAGE_T(J, D) do {                                                   \
    stage_half(pA0 + (J) * 64, As + (D) * 16384, wid);                       \
    stage_half(pA1 + (J) * 64, As + (D) * 16384 + 8192, wid);                \
    stage_half(pB0 + (J) * 64, Bs + (D) * 16384, wid);                       \
    stage_half(pB1 + (J) * 64, Bs + (D) * 16384 + 8192, wid);                \
  } while (0)

// ---- one K-tile, current buffer = buf0 (even kt) ----
#define TILE_E(KT) do {                                                      \
    /* sub0: q00 | read B1(kt) [buf0 c1] */                                  \
    PRIO1; RD_B(bS1, 4096, 6144); MMA8(0, 0, aS0, bS0); PRIO0; LGKM0; SB;    \
    /* sub1: q01 | read A1(kt) [buf0 h1] */                                  \
    PRIO1; RD_A(aS1, 8192, 10240, 12288, 14336); MMA8(0, 1, aS0, bS1);       \
    PRIO0; LGKM0; SB;                                                        \
    /* sub2: confirm kt+1, free buf0, stage kt+2; q11 | read A0(kt+1) */     \
    if ((KT) < 7) { VMC0; }                                                  \
    BAR;                                                                     \
    if ((KT) <= 5) STAGE_T((KT) + 2, 0);                                     \
    PRIO1;                                                                   \
    if ((KT) < 7) RD_A(aS0, 32768, 34816, 36864, 38912);                     \
    MMA8(1, 1, aS1, bS1); PRIO0; LGKM0; SB;                                  \
    /* sub3: q10 | read B0(kt+1) [buf1 c0] (after q10: WAR on bS0) */        \
    PRIO1; MMA8(1, 0, aS1, bS0); PRIO0;                                      \
    if ((KT) < 7) RD_B(bS0, 32768, 34816);                                   \
    LGKM0; SB;                                                               \
  } while (0)

// ---- one K-tile, current buffer = buf1 (odd kt) ----
#define TILE_O(KT) do {                                                      \
    PRIO1; RD_B(bS1, 36864, 38912); MMA8(0, 0, aS0, bS0); PRIO0; LGKM0; SB;  \
    PRIO1; RD_A(aS1, 40960, 43008, 45056, 47104); MMA8(0, 1, aS0, bS1);      \
    PRIO0; LGKM0; SB;                                                        \
    if ((KT) < 7) { VMC0; }                                                  \
    BAR;                                                                     \
    if ((KT) <= 5) STAGE_T((KT) + 2, 1);                                     \
    PRIO1;                                                                   \
    if ((KT) < 7) RD_A(aS0, 0, 2048, 4096, 6144);                            \
    MMA8(1, 1, aS1, bS1); PRIO0; LGKM0; SB;                                  \
    PRIO1; MMA8(1, 0, aS1, bS0); PRIO0;                                      \
    if ((KT) < 7) RD_B(bS0, 0, 2048);                                        \
    LGKM0; SB;                                                               \
  } while (0)

__global__ __launch_bounds__(512, 2) void gemm256(
    const bfr_t* __restrict__ A, const bfr_t* __restrict__ Bt,
    bfr_t* __restrict__ Cout, const float* __restrict__ bias, int M) {
  __shared__ short lds[65536];          // 128 KB
  short* As = lds;                      // [2 buf][2 half][128][64]
  short* Bs = lds + 32768;

  // --- bijective XCD-chunk swizzle (nwg % 8 == 0), y fastest in-chunk ---
  int nwg = gridDim.x;
  int gy = M >> 8;                      // M-blocks (6 for QKV, 2 for Wout)
  int bid = blockIdx.x;
  int logical = (bid & 7) * (nwg >> 3) + (bid >> 3);
  int perz = (LL / 256) * gy;
  int bz = logical / perz;
  int rem = logical - bz * perz;
  int bx = rem / gy;
  int by = rem - bx * gy;

  int m0 = by * 256, n0 = bx * 256;
  int t = threadIdx.x, lane = t & 63, wid = t >> 6;
  int quad = lane >> 4, r16 = lane & 15;
  int wm = wid >> 2, wn = wid & 3;
  // staging source offset: row (lane>>3), pre-swizzled granule (l&7)^(l>>3)
  int soff = (lane >> 3) * 512 + (((lane & 7) ^ (lane >> 3)) * 8);
  // ds_read swizzled k-granule slots (shorts): slot = gran ^ (row&7), x8
  int slot0 = (quad ^ (lane & 7)) * 8;          // k 0..31
  int slot1 = ((4 + quad) ^ (lane & 7)) * 8;    // k 32..63

  unsigned lb = (unsigned)(uintptr_t)(__attribute__((address_space(3))) short*)lds;
  unsigned aAs0 = lb + (unsigned)(wm * 16384 + r16 * 128 + slot0 * 2);
  unsigned aAs1 = lb + (unsigned)(wm * 16384 + r16 * 128 + slot1 * 2);
  unsigned bbase = 65536u + (unsigned)((wn >> 1) * 16384 + ((wn & 1) * 64 + r16) * 128);
  unsigned bBs0 = lb + bbase + (unsigned)(slot0 * 2);
  unsigned bBs1 = lb + bbase + (unsigned)(slot1 * 2);

  const bfr_t* pA0 = A + (size_t)m0 * 512 + soff;
  const bfr_t* pA1 = pA0 + (size_t)128 * 512;
  const bfr_t* pB0 = Bt + (size_t)bz * LL * 512 + (size_t)n0 * 512 + soff;
  const bfr_t* pB1 = pB0 + (size_t)128 * 512;

  f32x4 acc[8][4] = {};
  short8 aS0[8], aS1[8];
  short8 bS0[4], bS1[4];

  // ---- prologue: stage K-tiles 0 and 1; read q00 frags of tile 0 ----
  STAGE_T(0, 0);
  STAGE_T(1, 1);
  asm volatile("s_waitcnt vmcnt(8)" ::: "memory");   // tile 0 landed
  BAR;
  RD_A(aS0, 0, 2048, 4096, 6144);     // A0(t0)
  RD_B(bS0, 0, 2048);                 // B0(t0)
  LGKM0; SB;

  TILE_E(0); TILE_O(1); TILE_E(2); TILE_O(3);
  TILE_E(4); TILE_O(5); TILE_E(6); TILE_O(7);

  // ---- epilogue: C write (+bias) ----
  bfr_t* Cb = Cout + (size_t)bz * M * LL;
  int crow = m0 + wm * 128 + quad * 4;
  int ccol = n0 + wn * 64 + r16;
#pragma unroll
  for (int am = 0; am < 8; ++am) {
    int rbase = crow + (am >> 2) * 64 + (am & 3) * 16;
#pragma unroll
    for (int reg = 0; reg < 4; ++reg) {
      int row = rbase + reg;
      float bi = bias ? bias[row] : 0.f;
#pragma unroll
      for (int an = 0; an < 4; ++an) {
        int col = ccol + (an >> 1) * 32 + (an & 1) * 16;
        Cb[(size_t)row * LL + col] = f2bf(acc[am][an][reg] + bi);
      }
    }
  }
}

// --------- context partials via MFMA: ctx_p[bh][s][d][e], n split 8 ---------
__global__ __launch_bounds__(256) void context_mfma(
    const bfr_t* __restrict__ qkv, float* __restrict__ ctx_p,
    float* __restrict__ ksum_p) {
  __shared__ float red[4][4096];      // 64 KB: per-wave 64x64 partial
  int s = blockIdx.x, bh = blockIdx.y;
  int b = bh >> 3, h = bh & 7;
  int t = threadIdx.x, lane = t & 63, wid = t >> 6;
  int quad = lane >> 4, r = lane & 15;
  const bfr_t* kb = qkv + ((size_t)b * TC + 512 + h * 64) * LL;   // raw k rows
  const bfr_t* vb = qkv + ((size_t)b * TC + 1024 + h * 64) * LL;  // v rows
  int n_base = s * 512 + wid * 128;
  f32x4 acc[4][4] = {};
  float ps[4] = {};                    // per-lane exp-sum partials, row d=i*16+r
#pragma unroll
  for (int ks = 0; ks < 4; ++ks) {
    int n0 = n_base + ks * 32;
    short8 af[4], bf8[4];
#pragma unroll
    for (int i = 0; i < 4; ++i) {
      union { short s[8]; short8 v8; } uk;
      uk.v8 = *(const short8*)&kb[(size_t)(i * 16 + r) * LL + n0 + quad * 8];
#pragma unroll
      for (int jj = 0; jj < 8; ++jj) {
        float e = __expf(bf2f((bfr_t)uk.s[jj]));
        uk.s[jj] = (short)f2bf(e);
        ps[i] += e;
      }
      af[i] = uk.v8;
      bf8[i] = *(const short8*)&vb[(size_t)(i * 16 + r) * LL + n0 + quad * 8];
    }
#pragma unroll
    for (int i = 0; i < 4; ++i)
#pragma unroll
      for (int j = 0; j < 4; ++j)
        acc[i][j] = __builtin_amdgcn_mfma_f32_16x16x32_bf16(af[i], bf8[j],
                                                            acc[i][j], 0, 0, 0);
  }
  // ksum: reduce across the quad lanes holding the same row d
#pragma unroll
  for (int i = 0; i < 4; ++i) {
    ps[i] += __shfl_xor(ps[i], 16, 64);
    ps[i] += __shfl_xor(ps[i], 32, 64);
  }
  if (quad == 0) {
#pragma unroll
    for (int i = 0; i < 4; ++i) red[wid][i * 16 + r] = ps[i];
  }
  __syncthreads();
  if (t < 64)
    ksum_p[((size_t)bh * 8 + s) * 64 + t] =
        red[0][t] + red[1][t] + red[2][t] + red[3][t];
  __syncthreads();
  // each wave writes its 64x64 partial to its LDS quadrant, then block-sum
#pragma unroll
  for (int i = 0; i < 4; ++i)
#pragma unroll
    for (int j = 0; j < 4; ++j)
#pragma unroll
      for (int reg = 0; reg < 4; ++reg)
        red[wid][(i * 16 + quad * 4 + reg) * 64 + j * 16 + r] = acc[i][j][reg];
  __syncthreads();
  float* out = ctx_p + ((size_t)bh * 8 + s) * 4096;
#pragma unroll
  for (int u = 0; u < 16; ++u) {
    int idx = u * 256 + t;
    out[idx] = red[0][idx] + red[1][idx] + red[2][idx] + red[3][idx];
  }
}

// ------- reduce partials, apply 1/Z -> ctx_bf[bh][d][e] (bf16) --------------
__global__ __launch_bounds__(256) void context_reduce(
    const float* __restrict__ ctx_p, const float* __restrict__ ksum_p,
    bfr_t* __restrict__ ctx_bf) {
  __shared__ float zinv[64];
  int bh = blockIdx.x;
  int t = threadIdx.x;
  if (t < 64) {
    float s = 0.f;
#pragma unroll
    for (int s8 = 0; s8 < 8; ++s8) s += ksum_p[((size_t)bh * 8 + s8) * 64 + t];
    zinv[t] = 1.f / s;
  }
  __syncthreads();
#pragma unroll
  for (int i = 0; i < 16; ++i) {
    int idx = i * 256 + t;            // idx = d*64 + e
    int d = idx >> 6;
    float sum = 0.f;
#pragma unroll
    for (int s = 0; s < 8; ++s) sum += ctx_p[((size_t)bh * 8 + s) * 4096 + idx];
    ctx_bf[(size_t)bh * 4096 + idx] = f2bf(sum * zinv[d]);
  }
}

// --- fused q-softmax + apply: out_t[b][n][h*64+e] = softmax_d(q)^T ctx -----
__global__ __launch_bounds__(256) void apply_fused(
    const bfr_t* __restrict__ qkv, const bfr_t* __restrict__ ctx_bf,
    bfr_t* __restrict__ out_t) {
  int b = blockIdx.z, h = blockIdx.y;
  int t = threadIdx.x, lane = t & 63, wid = t >> 6;
  int quad = lane >> 4, r = lane & 15;
  int n0 = blockIdx.x * 256 + wid * 64;
  const bfr_t* qb = qkv + ((size_t)b * TC + h * 64) * LL;   // q rows [d][n]
  const bfr_t* cb = ctx_bf + (size_t)(b * HH + h) * 4096;   // [d][e]
  float v[4][16];
  float pm[4];
#pragma unroll
  for (int i = 0; i < 4; ++i) {
    pm[i] = -1e30f;
#pragma unroll
    for (int ks = 0; ks < 2; ++ks)
#pragma unroll
      for (int jj = 0; jj < 8; ++jj) {
        float q = bf2f(qb[(size_t)(ks * 32 + quad * 8 + jj) * LL + n0 + i * 16 + r]);
        v[i][ks * 8 + jj] = q;
        pm[i] = fmaxf(pm[i], q);
      }
  }
#pragma unroll
  for (int i = 0; i < 4; ++i) {
    pm[i] = fmaxf(pm[i], __shfl_xor(pm[i], 16, 64));
    pm[i] = fmaxf(pm[i], __shfl_xor(pm[i], 32, 64));
  }
  float psum[4];
#pragma unroll
  for (int i = 0; i < 4; ++i) {
    float s = 0.f;
#pragma unroll
    for (int u = 0; u < 16; ++u) { v[i][u] = __expf(v[i][u] - pm[i]); s += v[i][u]; }
    psum[i] = s;
  }
#pragma unroll
  for (int i = 0; i < 4; ++i) {
    psum[i] += __shfl_xor(psum[i], 16, 64);
    psum[i] += __shfl_xor(psum[i], 32, 64);
  }
  short8 af[2][4];
#pragma unroll
  for (int i = 0; i < 4; ++i) {
    float sc = SCALE_Q / psum[i];
#pragma unroll
    for (int ks = 0; ks < 2; ++ks) {
      union { short s[8]; short8 v8; } u;
#pragma unroll
      for (int jj = 0; jj < 8; ++jj) u.s[jj] = (short)f2bf(v[i][ks * 8 + jj] * sc);
      af[ks][i] = u.v8;
    }
  }
  short8 bfrag[2][4];
#pragma unroll
  for (int ks = 0; ks < 2; ++ks)
#pragma unroll
    for (int j = 0; j < 4; ++j) {
      union { short s[8]; short8 v8; } u;
#pragma unroll
      for (int jj = 0; jj < 8; ++jj)
        u.s[jj] = (short)cb[(ks * 32 + quad * 8 + jj) * 64 + j * 16 + r];
      bfrag[ks][j] = u.v8;
    }
  f32x4 acc[4][4] = {};
#pragma unroll
  for (int ks = 0; ks < 2; ++ks)
#pragma unroll
    for (int i = 0; i < 4; ++i)
#pragma unroll
      for (int j = 0; j < 4; ++j)
        acc[i][j] = __builtin_amdgcn_mfma_f32_16x16x32_bf16(af[ks][i], bfrag[ks][j],
                                                            acc[i][j], 0, 0, 0);
  bfr_t* dst = out_t + (size_t)b * LL * 512 + h * 64;
#pragma unroll
  for (int i = 0; i < 4; ++i)
#pragma unroll
    for (int reg = 0; reg < 4; ++reg) {
      int row = n0 + i * 16 + quad * 4 + reg;
#pragma unroll
      for (int j = 0; j < 4; ++j)
        dst[(size_t)row * 512 + j * 16 + r] = f2bf(acc[i][j][reg]);
    }
}

// ------------- final rmsnorm over c + residual add (single-pass) -----------
__global__ __launch_bounds__(256) void final_norm_res(
    const bfr_t* __restrict__ o, const float* __restrict__ g,
    const float* __restrict__ x, float* __restrict__ out) {
  __shared__ float red[4][64];
  __shared__ float invn[64];
  int b = blockIdx.y, l0 = blockIdx.x * 64;
  int t = threadIdx.x, ll = t & 63, cg = t >> 6;
  const bfr_t* ob = o + (size_t)b * CC * LL + l0 + ll;
  unsigned pk[64];
  float ss = 0.f;
#pragma unroll
  for (int i = 0; i < 64; ++i) {
    int c = cg * 128 + 2 * i;
    unsigned u0 = ob[(size_t)c * LL];
    unsigned u1 = ob[(size_t)(c + 1) * LL];
    float v0 = bf2f((bfr_t)u0), v1 = bf2f((bfr_t)u1);
    ss += v0 * v0 + v1 * v1;
    pk[i] = u0 | (u1 << 16);
  }
  red[cg][ll] = ss;
  __syncthreads();
  if (cg == 0) {
    float s = red[0][ll] + red[1][ll] + red[2][ll] + red[3][ll];
    invn[ll] = SQRT_C / fmaxf(sqrtf(s), 1e-12f);
  }
  __syncthreads();
  float iv = invn[ll];
  const float* xb = x + (size_t)b * CC * LL + l0 + ll;
  float* outb = out + (size_t)b * CC * LL + l0 + ll;
#pragma unroll
  for (int i = 0; i < 64; ++i) {
    int c = cg * 128 + 2 * i;
    float v0 = bf2f((bfr_t)(pk[i] & 0xffffu));
    float v1 = bf2f((bfr_t)(pk[i] >> 16));
    outb[(size_t)c * LL] = v0 * g[c] * iv + xb[(size_t)c * LL];
    outb[(size_t)(c + 1) * LL] = v1 * g[c + 1] * iv + xb[(size_t)(c + 1) * LL];
  }
}

// ---------------------------------------------------------------------------
extern "C" void kernel_launch(void* const* d_in, const int* in_sizes, int n_in,
                              void* d_out, int out_size, void* d_ws,
                              size_t ws_size, hipStream_t stream) {
  const float* x     = (const float*)d_in[0];
  const float* g_in  = (const float*)d_in[1];
  const float* w_qkv = (const float*)d_in[2];
  const float* w_out = (const float*)d_in[3];
  const float* b_out = (const float*)d_in[4];
  const float* g_out = (const float*)d_in[5];
  float* out = (float*)d_out;

  // workspace layout (bytes)
  char* ws = (char*)d_ws;
  const size_t off_wqkv  = 0;                       // 1536*512*2 = 1,572,864
  const size_t off_wout  = 1572864;                 // 512*512*2  =   524,288
  const size_t off_ksump = 2097152;                 // 64*8*64*4  =   131,072
  const size_t off_ctx   = 2260992;                 // 64*64*64*2 =   524,288 (bf16)
  const size_t off_ctxp  = 3309568;                 // 64*8*4096*4 = 8,388,608
  const size_t off_xt    = 11698176;                // 32MB  (xn_t, later out_t)
  const size_t off_qkv   = 45252608;                // 96MB  (later o_bf)
  const size_t ws_need   = 145915904;
  if (ws_size < ws_need) return;   // insufficient scratch -> fail loudly

  bfr_t* wqkv_bf = (bfr_t*)(ws + off_wqkv);
  bfr_t* wout_bf = (bfr_t*)(ws + off_wout);
  float* ksum_p  = (float*)(ws + off_ksump);
  bfr_t* ctx_bf  = (bfr_t*)(ws + off_ctx);
  float* ctxp    = (float*)(ws + off_ctxp);
  bfr_t* xt      = (bfr_t*)(ws + off_xt);    // xn_t then out_t (disjoint lifetimes)
  bfr_t* qkv     = (bfr_t*)(ws + off_qkv);
  bfr_t* o_bf    = (bfr_t*)(ws + off_qkv);   // overwrites dead q/k/v after apply

  // 1. weights -> bf16 (single vectorized launch)
  conv_bf16_2<<<dim3((1536 * 512 + 512 * 512) / 8 / 256), 256, 0, stream>>>(
      w_qkv, wqkv_bf, 1536 * 512, w_out, wout_bf, 512 * 512);
  // 2. fused input rmsnorm + transpose -> bf16 xt
  fused_norm_transpose<<<dim3(LL / 64, BB), 256, 0, stream>>>(x, g_in, xt);
  // 3. qkv = W_qkv @ xn   (register-pipelined 256^2 GEMM)
  gemm256<<<dim3((LL / 256) * (TC / 256) * BB), 512, 0, stream>>>(wqkv_bf, xt, qkv, nullptr, TC);
  // 4. context = exp(k) v^T via MFMA (exp + ksum inline), reduce + 1/Z -> bf16
  context_mfma<<<dim3(8, BB * HH), 256, 0, stream>>>(qkv, ctxp, ksum_p);
  context_reduce<<<dim3(BB * HH), 256, 0, stream>>>(ctxp, ksum_p, ctx_bf);
  // 5. fused q-softmax + apply -> out_t (xn_t now dead)
  apply_fused<<<dim3(LL / 256, HH, BB), 256, 0, stream>>>(qkv, ctx_bf, xt);
  // 6. o = W_out @ out + b_out   (qkv fully dead now)
  gemm256<<<dim3((LL / 256) * (CC / 256) * BB), 512, 0, stream>>>(wout_bf, xt, o_bf, b_out, CC);
  // 7. final rmsnorm + residual -> fp32 out
  final_norm_res<<<dim3(LL / 64, BB), 256, 0, stream>>>(o_bf, g_out, x, out);
}